// Round 1
// baseline (3210.291 us; speedup 1.0000x reference)
//
#include <hip/hip_runtime.h>
#include <math.h>

#define NEG_SLOPE 0.2f

static __device__ __forceinline__ unsigned int encf(float f) {
  unsigned int u = __float_as_uint(f);
  return (u & 0x80000000u) ? ~u : (u | 0x80000000u);
}
static __device__ __forceinline__ float decf(unsigned int k) {
  return __uint_as_float((k & 0x80000000u) ? (k ^ 0x80000000u) : ~k);
}
static __device__ __forceinline__ float lrelu(float v) {
  return v >= 0.f ? v : NEG_SLOPE * v;
}

// ---------------- GEMM1: h1 = x @ W1  (M x 128) @ (128 x 256) ----------------
#define BM 64
#define BN 64
#define BK 16
__global__ __launch_bounds__(256) void gemm1_kernel(
    const float* __restrict__ A, const float* __restrict__ B,
    float* __restrict__ C, int M, int N, int K) {
  __shared__ float As[BK][BM + 1];
  __shared__ float Bs[BK][BN + 1];
  const int bm = blockIdx.x * BM, bn = blockIdx.y * BN;
  const int tid = threadIdx.x;
  const int tr = tid / 16, tc = tid % 16;
  float acc[4][4] = {};
  for (int k0 = 0; k0 < K; k0 += BK) {
    {
      int r = tid / 4;
      int c = (tid % 4) * 4;
      int row = bm + r;
      float4 v = (row < M) ? *(const float4*)&A[(size_t)row * K + k0 + c]
                           : make_float4(0.f, 0.f, 0.f, 0.f);
      As[c + 0][r] = v.x; As[c + 1][r] = v.y;
      As[c + 2][r] = v.z; As[c + 3][r] = v.w;
    }
    {
      int r = tid / 16, c = (tid % 16) * 4;
      float4 v = *(const float4*)&B[(size_t)(k0 + r) * N + bn + c];
      Bs[r][c + 0] = v.x; Bs[r][c + 1] = v.y;
      Bs[r][c + 2] = v.z; Bs[r][c + 3] = v.w;
    }
    __syncthreads();
#pragma unroll
    for (int kk = 0; kk < BK; ++kk) {
      float a[4], b[4];
#pragma unroll
      for (int i = 0; i < 4; i++) a[i] = As[kk][tr * 4 + i];
#pragma unroll
      for (int j = 0; j < 4; j++) b[j] = Bs[kk][tc * 4 + j];
#pragma unroll
      for (int i = 0; i < 4; i++)
#pragma unroll
        for (int j = 0; j < 4; j++) acc[i][j] += a[i] * b[j];
    }
    __syncthreads();
  }
#pragma unroll
  for (int i = 0; i < 4; i++) {
    int row = bm + tr * 4 + i;
    if (row < M) {
#pragma unroll
      for (int j = 0; j < 4; j++)
        C[(size_t)row * N + bn + tc * 4 + j] = acc[i][j];
    }
  }
}

// ---------------- alpha1: per-(node,head) attention logits ----------------
__global__ void alpha1_kernel(const float* __restrict__ h1,
                              const float* __restrict__ a_src,
                              const float* __restrict__ a_dst,
                              float* __restrict__ as1, float* __restrict__ ad1,
                              int N) {
  int idx = blockIdx.x * blockDim.x + threadIdx.x;
  if (idx >= N * 8) return;
  int h = idx & 7;
  int n = idx >> 3;
  const float* hp = h1 + (size_t)n * 256 + h * 32;
  const float* sp = a_src + h * 32;
  const float* dp = a_dst + h * 32;
  float s = 0.f, d = 0.f;
#pragma unroll
  for (int c = 0; c < 32; c++) {
    float v = hp[c];
    s += v * sp[c];
    d += v * dp[c];
  }
  as1[idx] = s;
  ad1[idx] = d;
}

// ---------------- layer-1 edge softmax passes ----------------
__global__ void edge_max1(const int* __restrict__ ei, int E, int N,
                          const float* __restrict__ as1,
                          const float* __restrict__ ad1,
                          unsigned int* __restrict__ m1) {
  int idx = blockIdx.x * blockDim.x + threadIdx.x;
  int tot = (E + N) * 8;
  if (idx >= tot) return;
  int h = idx & 7, e = idx >> 3;
  int src, dst;
  if (e < E) { src = ei[e]; dst = ei[E + e]; } else { src = dst = e - E; }
  float v = lrelu(as1[src * 8 + h] + ad1[dst * 8 + h]);
  atomicMax(&m1[dst * 8 + h], encf(v));
}

__global__ void edge_sum1(const int* __restrict__ ei, int E, int N,
                          const float* __restrict__ as1,
                          const float* __restrict__ ad1,
                          const unsigned int* __restrict__ m1,
                          float* __restrict__ s1) {
  int idx = blockIdx.x * blockDim.x + threadIdx.x;
  int tot = (E + N) * 8;
  if (idx >= tot) return;
  int h = idx & 7, e = idx >> 3;
  int src, dst;
  if (e < E) { src = ei[e]; dst = ei[E + e]; } else { src = dst = e - E; }
  float v = lrelu(as1[src * 8 + h] + ad1[dst * 8 + h]);
  float m = decf(m1[dst * 8 + h]);
  atomicAdd(&s1[dst * 8 + h], expf(v - m));
}

// ---------------- layer-1 message pass: one wave per edge ----------------
__global__ __launch_bounds__(256) void message1(
    const int* __restrict__ ei, int E, int N,
    const float* __restrict__ as1, const float* __restrict__ ad1,
    const unsigned int* __restrict__ m1, const float* __restrict__ s1,
    const float* __restrict__ h1, float* __restrict__ out1) {
  int wave = (int)((blockIdx.x * (size_t)blockDim.x + threadIdx.x) >> 6);
  int lane = threadIdx.x & 63;
  if (wave >= E + N) return;
  int e = wave;
  int src, dst;
  if (e < E) { src = ei[e]; dst = ei[E + e]; } else { src = dst = e - E; }
  int h = lane >> 3;
  float v = lrelu(as1[src * 8 + h] + ad1[dst * 8 + h]);
  float m = decf(m1[dst * 8 + h]);
  float s = s1[dst * 8 + h];
  float alpha = expf(v - m) / (s + 1e-16f);
  float4 hv = *(const float4*)&h1[(size_t)src * 256 + lane * 4];
  float* op = &out1[(size_t)dst * 256 + lane * 4];
  atomicAdd(op + 0, alpha * hv.x);
  atomicAdd(op + 1, alpha * hv.y);
  atomicAdd(op + 2, alpha * hv.z);
  atomicAdd(op + 3, alpha * hv.w);
}

// ---------------- ELU(out1 + b1) -> h2 ----------------
__global__ void elu_bias(const float* __restrict__ out1,
                         const float* __restrict__ b1,
                         float* __restrict__ h2, int total) {
  int i = blockIdx.x * blockDim.x + threadIdx.x;
  if (i >= total) return;
  float v = out1[i] + b1[i & 255];
  h2[i] = v > 0.f ? v : (expf(v) - 1.f);
}

// ---------------- layer-2 projection: g = h2 @ W2, plus alpha2 ----------------
__global__ __launch_bounds__(256) void layer2_proj(
    const float* __restrict__ h2, const float* __restrict__ W2,
    const float* __restrict__ a_src2, const float* __restrict__ a_dst2,
    float* __restrict__ g, float* __restrict__ as2, float* __restrict__ ad2,
    int N) {
  int wid = (int)((blockIdx.x * (size_t)blockDim.x + threadIdx.x) >> 6);
  int lane = threadIdx.x & 63;
  if (wid >= N) return;
  float4 hv = *(const float4*)&h2[(size_t)wid * 256 + lane * 4];
  float acc[10];
  int k = lane * 4;
#pragma unroll
  for (int c = 0; c < 10; c++) {
    acc[c] = hv.x * W2[(k + 0) * 10 + c] + hv.y * W2[(k + 1) * 10 + c] +
             hv.z * W2[(k + 2) * 10 + c] + hv.w * W2[(k + 3) * 10 + c];
  }
#pragma unroll
  for (int off = 32; off > 0; off >>= 1) {
#pragma unroll
    for (int c = 0; c < 10; c++) acc[c] += __shfl_xor(acc[c], off, 64);
  }
  if (lane < 10) g[(size_t)wid * 10 + lane] = acc[lane];
  if (lane == 0) {
    float s = 0.f, d = 0.f;
#pragma unroll
    for (int c = 0; c < 10; c++) {
      s += acc[c] * a_src2[c];
      d += acc[c] * a_dst2[c];
    }
    as2[wid] = s;
    ad2[wid] = d;
  }
}

// ---------------- layer-2 edge softmax passes ----------------
__global__ void edge_max2(const int* __restrict__ ei, int E, int N,
                          const float* __restrict__ as2,
                          const float* __restrict__ ad2,
                          unsigned int* __restrict__ m2) {
  int e = blockIdx.x * blockDim.x + threadIdx.x;
  if (e >= E + N) return;
  int src, dst;
  if (e < E) { src = ei[e]; dst = ei[E + e]; } else { src = dst = e - E; }
  float v = lrelu(as2[src] + ad2[dst]);
  atomicMax(&m2[dst], encf(v));
}

__global__ void edge_sum2(const int* __restrict__ ei, int E, int N,
                          const float* __restrict__ as2,
                          const float* __restrict__ ad2,
                          const unsigned int* __restrict__ m2,
                          float* __restrict__ s2) {
  int e = blockIdx.x * blockDim.x + threadIdx.x;
  if (e >= E + N) return;
  int src, dst;
  if (e < E) { src = ei[e]; dst = ei[E + e]; } else { src = dst = e - E; }
  float v = lrelu(as2[src] + ad2[dst]);
  float m = decf(m2[dst]);
  atomicAdd(&s2[dst], expf(v - m));
}

// ---------------- init d_out with bias b2 ----------------
__global__ void init_out(float* __restrict__ out, const float* __restrict__ b2,
                         int N) {
  int i = blockIdx.x * blockDim.x + threadIdx.x;
  if (i >= N * 10) return;
  out[i] = b2[i - (i / 10) * 10];
}

// ---------------- layer-2 message pass ----------------
__global__ void message2(const int* __restrict__ ei, int E, int N,
                         const float* __restrict__ as2,
                         const float* __restrict__ ad2,
                         const unsigned int* __restrict__ m2,
                         const float* __restrict__ s2,
                         const float* __restrict__ g,
                         float* __restrict__ out) {
  int idx = blockIdx.x * blockDim.x + threadIdx.x;
  int tot = (E + N) * 10;
  if (idx >= tot) return;
  int e = idx / 10;
  int c = idx - e * 10;
  int src, dst;
  if (e < E) { src = ei[e]; dst = ei[E + e]; } else { src = dst = e - E; }
  float v = lrelu(as2[src] + ad2[dst]);
  float m = decf(m2[dst]);
  float s = s2[dst];
  float alpha = expf(v - m) / (s + 1e-16f);
  atomicAdd(&out[(size_t)dst * 10 + c], alpha * g[(size_t)src * 10 + c]);
}

extern "C" void kernel_launch(void* const* d_in, const int* in_sizes, int n_in,
                              void* d_out, int out_size, void* d_ws,
                              size_t ws_size, hipStream_t stream) {
  const float* x      = (const float*)d_in[0];
  const int*   ei     = (const int*)d_in[1];
  const float* W1     = (const float*)d_in[2];
  const float* a_src1 = (const float*)d_in[3];
  const float* a_dst1 = (const float*)d_in[4];
  const float* b1     = (const float*)d_in[5];
  const float* W2     = (const float*)d_in[6];
  const float* a_src2 = (const float*)d_in[7];
  const float* a_dst2 = (const float*)d_in[8];
  const float* b2     = (const float*)d_in[9];
  float* out = (float*)d_out;

  const int N = in_sizes[0] / 128;   // 50000
  const int E = in_sizes[1] / 2;     // 800000
  const int ET = E + N;              // edges incl. self-loops

  float* ws = (float*)d_ws;
  float* h1   = ws;                       // N*256 (reused as h2)
  float* out1 = h1 + (size_t)N * 256;     // N*256
  float* as1  = out1 + (size_t)N * 256;   // N*8
  float* ad1  = as1 + (size_t)N * 8;      // N*8
  unsigned int* m1 = (unsigned int*)(ad1 + (size_t)N * 8);  // N*8
  float* s1   = (float*)m1 + (size_t)N * 8;                 // N*8
  float* g    = s1 + (size_t)N * 8;       // N*10
  float* as2  = g + (size_t)N * 10;       // N
  float* ad2  = as2 + N;                  // N
  unsigned int* m2 = (unsigned int*)(ad2 + N);              // N
  float* s2   = (float*)m2 + N;           // N

  // zero accumulators (m1 encoding: 0 == minimum key; every dst has a self-loop)
  hipMemsetAsync(out1, 0, (size_t)N * 256 * 4, stream);
  hipMemsetAsync(m1, 0, (size_t)N * 16 * 4, stream);   // m1 + s1
  hipMemsetAsync(m2, 0, (size_t)N * 2 * 4, stream);    // m2 + s2

  // ---- layer 1 ----
  dim3 g1((N + BM - 1) / BM, 256 / BN);
  gemm1_kernel<<<g1, 256, 0, stream>>>(x, W1, h1, N, 256, 128);

  alpha1_kernel<<<(N * 8 + 255) / 256, 256, 0, stream>>>(h1, a_src1, a_dst1,
                                                         as1, ad1, N);

  int eb1 = (ET * 8 + 255) / 256;
  edge_max1<<<eb1, 256, 0, stream>>>(ei, E, N, as1, ad1, m1);
  edge_sum1<<<eb1, 256, 0, stream>>>(ei, E, N, as1, ad1, m1, s1);

  message1<<<(ET + 3) / 4, 256, 0, stream>>>(ei, E, N, as1, ad1, m1, s1, h1,
                                             out1);

  // ---- ELU + bias -> h2 (reuse h1 buffer) ----
  elu_bias<<<((size_t)N * 256 + 255) / 256, 256, 0, stream>>>(out1, b1, h1,
                                                              N * 256);

  // ---- layer 2 ----
  layer2_proj<<<(N + 3) / 4, 256, 0, stream>>>(h1, W2, a_src2, a_dst2, g, as2,
                                               ad2, N);

  int eb2 = (ET + 255) / 256;
  edge_max2<<<eb2, 256, 0, stream>>>(ei, E, N, as2, ad2, m2);
  edge_sum2<<<eb2, 256, 0, stream>>>(ei, E, N, as2, ad2, m2, s2);

  init_out<<<(N * 10 + 255) / 256, 256, 0, stream>>>(out, b2, N);

  message2<<<(ET * 10 + 255) / 256, 256, 0, stream>>>(ei, E, N, as2, ad2, m2,
                                                      s2, g, out);
}

// Round 2
// 572.898 us; speedup vs baseline: 5.6036x; 5.6036x over previous
//
#include <hip/hip_runtime.h>
#include <math.h>

#define NEG_SLOPE 0.2f

static __device__ __forceinline__ float lrelu(float v) {
  return v >= 0.f ? v : NEG_SLOPE * v;
}

// ---------------- GEMM1: h1 = x @ W1  (M x 128) @ (128 x 256) ----------------
#define BM 64
#define BN 64
#define BK 16
__global__ __launch_bounds__(256) void gemm1_kernel(
    const float* __restrict__ A, const float* __restrict__ B,
    float* __restrict__ C, int M, int N, int K) {
  __shared__ float As[BK][BM + 1];
  __shared__ float Bs[BK][BN + 1];
  const int bm = blockIdx.x * BM, bn = blockIdx.y * BN;
  const int tid = threadIdx.x;
  const int tr = tid / 16, tc = tid % 16;
  float acc[4][4] = {};
  for (int k0 = 0; k0 < K; k0 += BK) {
    {
      int r = tid / 4;
      int c = (tid % 4) * 4;
      int row = bm + r;
      float4 v = (row < M) ? *(const float4*)&A[(size_t)row * K + k0 + c]
                           : make_float4(0.f, 0.f, 0.f, 0.f);
      As[c + 0][r] = v.x; As[c + 1][r] = v.y;
      As[c + 2][r] = v.z; As[c + 3][r] = v.w;
    }
    {
      int r = tid / 16, c = (tid % 16) * 4;
      float4 v = *(const float4*)&B[(size_t)(k0 + r) * N + bn + c];
      Bs[r][c + 0] = v.x; Bs[r][c + 1] = v.y;
      Bs[r][c + 2] = v.z; Bs[r][c + 3] = v.w;
    }
    __syncthreads();
#pragma unroll
    for (int kk = 0; kk < BK; ++kk) {
      float a[4], b[4];
#pragma unroll
      for (int i = 0; i < 4; i++) a[i] = As[kk][tr * 4 + i];
#pragma unroll
      for (int j = 0; j < 4; j++) b[j] = Bs[kk][tc * 4 + j];
#pragma unroll
      for (int i = 0; i < 4; i++)
#pragma unroll
        for (int j = 0; j < 4; j++) acc[i][j] += a[i] * b[j];
    }
    __syncthreads();
  }
#pragma unroll
  for (int i = 0; i < 4; i++) {
    int row = bm + tr * 4 + i;
    if (row < M) {
#pragma unroll
      for (int j = 0; j < 4; j++)
        C[(size_t)row * N + bn + tc * 4 + j] = acc[i][j];
    }
  }
}

// ---------------- alpha1: per-(node,head) attention logits ----------------
__global__ void alpha1_kernel(const float* __restrict__ h1,
                              const float* __restrict__ a_src,
                              const float* __restrict__ a_dst,
                              float* __restrict__ as1, float* __restrict__ ad1,
                              int N) {
  int idx = blockIdx.x * blockDim.x + threadIdx.x;
  if (idx >= N * 8) return;
  int h = idx & 7;
  int n = idx >> 3;
  const float* hp = h1 + (size_t)n * 256 + h * 32;
  const float* sp = a_src + h * 32;
  const float* dp = a_dst + h * 32;
  float s = 0.f, d = 0.f;
#pragma unroll
  for (int c = 0; c < 32; c++) {
    float v = hp[c];
    s += v * sp[c];
    d += v * dp[c];
  }
  as1[idx] = s;
  ad1[idx] = d;
}

// ---------------- CSR build ----------------
__global__ void deg_kernel(const int* __restrict__ ei, int E,
                           int* __restrict__ deg) {
  int e = blockIdx.x * blockDim.x + threadIdx.x;
  if (e < E) atomicAdd(&deg[ei[E + e]], 1);
}

// single-workgroup scan; also plants the self-loop in slot 0 of each bucket
__global__ __launch_bounds__(1024) void scan_kernel(
    int* __restrict__ degcur,  // in: degree, out: cursor (= row_start+1)
    int* __restrict__ row_start, int* __restrict__ csr, int N) {
  __shared__ int part[1024];
  const int t = threadIdx.x;
  const int chunk = (N + 1023) / 1024;
  const int beg = t * chunk;
  const int end = min(beg + chunk, N);
  int sum = 0;
  for (int i = beg; i < end; i++) sum += degcur[i] + 1;
  part[t] = sum;
  __syncthreads();
  for (int off = 1; off < 1024; off <<= 1) {
    int v = (t >= off) ? part[t - off] : 0;
    __syncthreads();
    part[t] += v;
    __syncthreads();
  }
  int p = (t == 0) ? 0 : part[t - 1];
  for (int i = beg; i < end; i++) {
    int d = degcur[i];
    row_start[i] = p;
    csr[p] = i;           // self-loop first
    degcur[i] = p + 1;    // cursor
    p += d + 1;
  }
  if (t == 1023) row_start[N] = part[1023];
}

__global__ void scatter_kernel(const int* __restrict__ ei, int E,
                               int* __restrict__ cursor,
                               int* __restrict__ csr) {
  int e = blockIdx.x * blockDim.x + threadIdx.x;
  if (e < E) {
    int dst = ei[E + e];
    int pos = atomicAdd(&cursor[dst], 1);
    csr[pos] = ei[e];
  }
}

// ---- layer-1 fused softmax + aggregate + bias + ELU: one wave per dst ----
__global__ __launch_bounds__(256) void agg1_kernel(
    const int* __restrict__ row_start, const int* __restrict__ csr,
    const float* __restrict__ as1, const float* __restrict__ ad1,
    const float* __restrict__ h1, const float* __restrict__ b1,
    float* __restrict__ h2, int N) {
  int dst = (int)((blockIdx.x * (size_t)blockDim.x + threadIdx.x) >> 6);
  int lane = threadIdx.x & 63;
  if (dst >= N) return;
  const int beg = row_start[dst];
  const int deg = row_start[dst + 1] - beg;

  // softmax stats: lane handles head hS = lane&7, edge subset grp = lane>>3
  const int hS = lane & 7;
  const int grp = lane >> 3;
  const float ad = ad1[dst * 8 + hS];
  float m = -INFINITY;
  for (int j = grp; j < deg; j += 8) {
    int src = csr[beg + j];
    m = fmaxf(m, lrelu(as1[src * 8 + hS] + ad));
  }
  m = fmaxf(m, __shfl_xor(m, 8, 64));
  m = fmaxf(m, __shfl_xor(m, 16, 64));
  m = fmaxf(m, __shfl_xor(m, 32, 64));
  float s = 0.f;
  for (int j = grp; j < deg; j += 8) {
    int src = csr[beg + j];
    s += expf(lrelu(as1[src * 8 + hS] + ad) - m);
  }
  s += __shfl_xor(s, 8, 64);
  s += __shfl_xor(s, 16, 64);
  s += __shfl_xor(s, 32, 64);

  // aggregation: lane owns channels [4*lane, 4*lane+4) -> head hA = lane>>3
  const int hA = lane >> 3;
  const float mA = __shfl(m, hA, 64);
  const float sA = __shfl(s, hA, 64);
  const float adA = __shfl(ad, hA, 64);
  const float inv = 1.f / (sA + 1e-16f);
  float4 acc = make_float4(0.f, 0.f, 0.f, 0.f);
  for (int j = 0; j < deg; ++j) {
    int src = csr[beg + j];
    float v = lrelu(as1[src * 8 + hA] + adA);
    float alpha = expf(v - mA) * inv;
    float4 hv = *(const float4*)&h1[(size_t)src * 256 + lane * 4];
    acc.x += alpha * hv.x;
    acc.y += alpha * hv.y;
    acc.z += alpha * hv.z;
    acc.w += alpha * hv.w;
  }
  float4 bv = *(const float4*)&b1[lane * 4];
  acc.x += bv.x; acc.y += bv.y; acc.z += bv.z; acc.w += bv.w;
  acc.x = acc.x > 0.f ? acc.x : (expf(acc.x) - 1.f);
  acc.y = acc.y > 0.f ? acc.y : (expf(acc.y) - 1.f);
  acc.z = acc.z > 0.f ? acc.z : (expf(acc.z) - 1.f);
  acc.w = acc.w > 0.f ? acc.w : (expf(acc.w) - 1.f);
  *(float4*)&h2[(size_t)dst * 256 + lane * 4] = acc;
}

// ---------------- layer-2 projection: g = h2 @ W2, plus alpha2 ----------------
__global__ __launch_bounds__(256) void layer2_proj(
    const float* __restrict__ h2, const float* __restrict__ W2,
    const float* __restrict__ a_src2, const float* __restrict__ a_dst2,
    float* __restrict__ g, float* __restrict__ as2, float* __restrict__ ad2,
    int N) {
  int wid = (int)((blockIdx.x * (size_t)blockDim.x + threadIdx.x) >> 6);
  int lane = threadIdx.x & 63;
  if (wid >= N) return;
  float4 hv = *(const float4*)&h2[(size_t)wid * 256 + lane * 4];
  float acc[10];
  int k = lane * 4;
#pragma unroll
  for (int c = 0; c < 10; c++) {
    acc[c] = hv.x * W2[(k + 0) * 10 + c] + hv.y * W2[(k + 1) * 10 + c] +
             hv.z * W2[(k + 2) * 10 + c] + hv.w * W2[(k + 3) * 10 + c];
  }
#pragma unroll
  for (int off = 32; off > 0; off >>= 1) {
#pragma unroll
    for (int c = 0; c < 10; c++) acc[c] += __shfl_xor(acc[c], off, 64);
  }
  if (lane < 10) g[(size_t)wid * 10 + lane] = acc[lane];
  if (lane == 0) {
    float s = 0.f, d = 0.f;
#pragma unroll
    for (int c = 0; c < 10; c++) {
      s += acc[c] * a_src2[c];
      d += acc[c] * a_dst2[c];
    }
    as2[wid] = s;
    ad2[wid] = d;
  }
}

// ---- layer-2 fused softmax + aggregate + bias: one wave per dst ----
__global__ __launch_bounds__(256) void agg2_kernel(
    const int* __restrict__ row_start, const int* __restrict__ csr,
    const float* __restrict__ as2, const float* __restrict__ ad2,
    const float* __restrict__ g, const float* __restrict__ b2,
    float* __restrict__ out, int N) {
  int dst = (int)((blockIdx.x * (size_t)blockDim.x + threadIdx.x) >> 6);
  int lane = threadIdx.x & 63;
  if (dst >= N) return;
  const int beg = row_start[dst];
  const int deg = row_start[dst + 1] - beg;
  const float ad = ad2[dst];
  float m = -INFINITY;
  for (int j = lane; j < deg; j += 64)
    m = fmaxf(m, lrelu(as2[csr[beg + j]] + ad));
#pragma unroll
  for (int off = 1; off < 64; off <<= 1) m = fmaxf(m, __shfl_xor(m, off, 64));
  float s = 0.f;
  for (int j = lane; j < deg; j += 64)
    s += expf(lrelu(as2[csr[beg + j]] + ad) - m);
#pragma unroll
  for (int off = 1; off < 64; off <<= 1) s += __shfl_xor(s, off, 64);
  const float inv = 1.f / (s + 1e-16f);
  if (lane < 10) {
    float acc = 0.f;
    for (int j = 0; j < deg; ++j) {
      int src = csr[beg + j];
      float alpha = expf(lrelu(as2[src] + ad) - m) * inv;
      acc += alpha * g[(size_t)src * 10 + lane];
    }
    out[(size_t)dst * 10 + lane] = acc + b2[lane];
  }
}

extern "C" void kernel_launch(void* const* d_in, const int* in_sizes, int n_in,
                              void* d_out, int out_size, void* d_ws,
                              size_t ws_size, hipStream_t stream) {
  const float* x      = (const float*)d_in[0];
  const int*   ei     = (const int*)d_in[1];
  const float* W1     = (const float*)d_in[2];
  const float* a_src1 = (const float*)d_in[3];
  const float* a_dst1 = (const float*)d_in[4];
  const float* b1     = (const float*)d_in[5];
  const float* W2     = (const float*)d_in[6];
  const float* a_src2 = (const float*)d_in[7];
  const float* a_dst2 = (const float*)d_in[8];
  const float* b2     = (const float*)d_in[9];
  float* out = (float*)d_out;

  const int N = in_sizes[0] / 128;   // 50000
  const int E = in_sizes[1] / 2;     // 800000
  const int ET = E + N;

  float* ws = (float*)d_ws;
  float* h1  = ws;                        // N*256
  float* h2  = h1 + (size_t)N * 256;      // N*256
  float* as1 = h2 + (size_t)N * 256;      // N*8
  float* ad1 = as1 + (size_t)N * 8;       // N*8
  float* g   = ad1 + (size_t)N * 8;       // N*10
  float* as2 = g + (size_t)N * 10;        // N
  float* ad2 = as2 + N;                   // N
  int* cursor    = (int*)(ad2 + N);       // N (deg, then cursor)
  int* row_start = cursor + N;            // N+1
  int* csr       = row_start + N + 1;     // E+N

  hipMemsetAsync(cursor, 0, (size_t)N * 4, stream);

  // ---- CSR build (shared by both layers) ----
  deg_kernel<<<(E + 255) / 256, 256, 0, stream>>>(ei, E, cursor);
  scan_kernel<<<1, 1024, 0, stream>>>(cursor, row_start, csr, N);
  scatter_kernel<<<(E + 255) / 256, 256, 0, stream>>>(ei, E, cursor, csr);

  // ---- layer 1 ----
  dim3 g1((N + BM - 1) / BM, 256 / BN);
  gemm1_kernel<<<g1, 256, 0, stream>>>(x, W1, h1, N, 256, 128);
  alpha1_kernel<<<(N * 8 + 255) / 256, 256, 0, stream>>>(h1, a_src1, a_dst1,
                                                         as1, ad1, N);
  agg1_kernel<<<(N + 3) / 4, 256, 0, stream>>>(row_start, csr, as1, ad1, h1,
                                               b1, h2, N);

  // ---- layer 2 ----
  layer2_proj<<<(N + 3) / 4, 256, 0, stream>>>(h2, W2, a_src2, a_dst2, g, as2,
                                               ad2, N);
  agg2_kernel<<<(N + 3) / 4, 256, 0, stream>>>(row_start, csr, as2, ad2, g, b2,
                                               out, N);
}

// Round 3
// 477.122 us; speedup vs baseline: 6.7284x; 1.2007x over previous
//
#include <hip/hip_runtime.h>
#include <math.h>

#define NEG_SLOPE 0.2f

static __device__ __forceinline__ float lrelu(float v) {
  return v >= 0.f ? v : NEG_SLOPE * v;
}
static __device__ __forceinline__ unsigned short f2bf(float f) {
  unsigned u = __float_as_uint(f);
  u = u + 0x7FFFu + ((u >> 16) & 1u);  // RNE
  return (unsigned short)(u >> 16);
}
static __device__ __forceinline__ float bf2f(unsigned short b) {
  return __uint_as_float(((unsigned)b) << 16);
}

// ------- GEMM1: h1 = x @ W1 (M x 128)@(128 x 256), writes f32 + bf16 -------
#define BM 64
#define BN 64
#define BK 16
__global__ __launch_bounds__(256) void gemm1_kernel(
    const float* __restrict__ A, const float* __restrict__ B,
    float* __restrict__ C, unsigned short* __restrict__ Cb, int M, int N,
    int K) {
  __shared__ float As[BK][BM + 1];
  __shared__ float Bs[BK][BN + 1];
  const int bm = blockIdx.x * BM, bn = blockIdx.y * BN;
  const int tid = threadIdx.x;
  const int tr = tid / 16, tc = tid % 16;
  float acc[4][4] = {};
  for (int k0 = 0; k0 < K; k0 += BK) {
    {
      int r = tid / 4;
      int c = (tid % 4) * 4;
      int row = bm + r;
      float4 v = (row < M) ? *(const float4*)&A[(size_t)row * K + k0 + c]
                           : make_float4(0.f, 0.f, 0.f, 0.f);
      As[c + 0][r] = v.x; As[c + 1][r] = v.y;
      As[c + 2][r] = v.z; As[c + 3][r] = v.w;
    }
    {
      int r = tid / 16, c = (tid % 16) * 4;
      float4 v = *(const float4*)&B[(size_t)(k0 + r) * N + bn + c];
      Bs[r][c + 0] = v.x; Bs[r][c + 1] = v.y;
      Bs[r][c + 2] = v.z; Bs[r][c + 3] = v.w;
    }
    __syncthreads();
#pragma unroll
    for (int kk = 0; kk < BK; ++kk) {
      float a[4], b[4];
#pragma unroll
      for (int i = 0; i < 4; i++) a[i] = As[kk][tr * 4 + i];
#pragma unroll
      for (int j = 0; j < 4; j++) b[j] = Bs[kk][tc * 4 + j];
#pragma unroll
      for (int i = 0; i < 4; i++)
#pragma unroll
        for (int j = 0; j < 4; j++) acc[i][j] += a[i] * b[j];
    }
    __syncthreads();
  }
#pragma unroll
  for (int i = 0; i < 4; i++) {
    int row = bm + tr * 4 + i;
    if (row < M) {
      *(float4*)&C[(size_t)row * N + bn + tc * 4] =
          make_float4(acc[i][0], acc[i][1], acc[i][2], acc[i][3]);
      ushort4 hb;
      hb.x = f2bf(acc[i][0]); hb.y = f2bf(acc[i][1]);
      hb.z = f2bf(acc[i][2]); hb.w = f2bf(acc[i][3]);
      *(ushort4*)&Cb[(size_t)row * N + bn + tc * 4] = hb;
    }
  }
}

// ---------------- alpha1: per-(node,head) attention logits ----------------
__global__ void alpha1_kernel(const float* __restrict__ h1,
                              const float* __restrict__ a_src,
                              const float* __restrict__ a_dst,
                              float* __restrict__ as1, float* __restrict__ ad1,
                              int N) {
  int idx = blockIdx.x * blockDim.x + threadIdx.x;
  if (idx >= N * 8) return;
  int h = idx & 7;
  int n = idx >> 3;
  const float* hp = h1 + (size_t)n * 256 + h * 32;
  const float* sp = a_src + h * 32;
  const float* dp = a_dst + h * 32;
  float s = 0.f, d = 0.f;
#pragma unroll
  for (int c = 0; c < 32; c++) {
    float v = hp[c];
    s += v * sp[c];
    d += v * dp[c];
  }
  as1[idx] = s;
  ad1[idx] = d;
}

// ---------------- CSR build ----------------
__global__ void deg_kernel(const int* __restrict__ ei, int E,
                           int* __restrict__ deg) {
  int e = blockIdx.x * blockDim.x + threadIdx.x;
  if (e < E) atomicAdd(&deg[ei[E + e]], 1);
}

__global__ __launch_bounds__(1024) void scan_kernel(
    int* __restrict__ degcur, int* __restrict__ row_start,
    int* __restrict__ csr, int N) {
  __shared__ int part[1024];
  const int t = threadIdx.x;
  const int chunk = (N + 1023) / 1024;
  const int beg = t * chunk;
  const int end = min(beg + chunk, N);
  int sum = 0;
  for (int i = beg; i < end; i++) sum += degcur[i] + 1;
  part[t] = sum;
  __syncthreads();
  for (int off = 1; off < 1024; off <<= 1) {
    int v = (t >= off) ? part[t - off] : 0;
    __syncthreads();
    part[t] += v;
    __syncthreads();
  }
  int p = (t == 0) ? 0 : part[t - 1];
  for (int i = beg; i < end; i++) {
    int d = degcur[i];
    row_start[i] = p;
    csr[p] = i;           // self-loop first
    degcur[i] = p + 1;    // cursor
    p += d + 1;
  }
  if (t == 1023) row_start[N] = part[1023];
}

__global__ void scatter_kernel(const int* __restrict__ ei, int E,
                               int* __restrict__ cursor,
                               int* __restrict__ csr) {
  int e = blockIdx.x * blockDim.x + threadIdx.x;
  if (e < E) {
    int dst = ei[E + e];
    int pos = atomicAdd(&cursor[dst], 1);
    csr[pos] = ei[e];
  }
}

// ---- layer-1 fused: softmax + bf16 gather-aggregate + bias + ELU +
// ----               W2 projection + alpha2 logits.  One wave per dst. ----
__global__ __launch_bounds__(256) void agg1_kernel(
    const int* __restrict__ row_start, const int* __restrict__ csr,
    const float* __restrict__ as1, const float* __restrict__ ad1,
    const unsigned short* __restrict__ h1b, const float* __restrict__ b1,
    const float* __restrict__ W2, const float* __restrict__ a_src2,
    const float* __restrict__ a_dst2, float* __restrict__ g,
    float* __restrict__ as2, float* __restrict__ ad2, int N) {
  int dst = (int)((blockIdx.x * (size_t)blockDim.x + threadIdx.x) >> 6);
  int lane = threadIdx.x & 63;
  if (dst >= N) return;
  const int beg = row_start[dst];
  const int deg = row_start[dst + 1] - beg;

  // softmax stats: lane handles head hS = lane&7, edge subset grp = lane>>3
  const int hS = lane & 7;
  const int grp = lane >> 3;
  const float ad = ad1[dst * 8 + hS];
  float m = -INFINITY;
  for (int j = grp; j < deg; j += 8) {
    int src = csr[beg + j];
    m = fmaxf(m, lrelu(as1[src * 8 + hS] + ad));
  }
  m = fmaxf(m, __shfl_xor(m, 8, 64));
  m = fmaxf(m, __shfl_xor(m, 16, 64));
  m = fmaxf(m, __shfl_xor(m, 32, 64));
  float s = 0.f;
  for (int j = grp; j < deg; j += 8) {
    int src = csr[beg + j];
    s += expf(lrelu(as1[src * 8 + hS] + ad) - m);
  }
  s += __shfl_xor(s, 8, 64);
  s += __shfl_xor(s, 16, 64);
  s += __shfl_xor(s, 32, 64);

  // aggregation: lane owns channels [4*lane, 4*lane+4) -> head hA = lane>>3
  const int hA = lane >> 3;
  const float mA = __shfl(m, hA, 64);
  const float sA = __shfl(s, hA, 64);
  const float adA = __shfl(ad, hA, 64);
  const float inv = 1.f / (sA + 1e-16f);
  float4 acc = make_float4(0.f, 0.f, 0.f, 0.f);
  for (int j = 0; j < deg; ++j) {
    int src = csr[beg + j];
    float v = lrelu(as1[src * 8 + hA] + adA);
    float alpha = expf(v - mA) * inv;
    ushort4 hv = *(const ushort4*)&h1b[(size_t)src * 256 + lane * 4];
    acc.x += alpha * bf2f(hv.x);
    acc.y += alpha * bf2f(hv.y);
    acc.z += alpha * bf2f(hv.z);
    acc.w += alpha * bf2f(hv.w);
  }
  float4 bv = *(const float4*)&b1[lane * 4];
  float v0 = acc.x + bv.x, v1 = acc.y + bv.y;
  float v2 = acc.z + bv.z, v3 = acc.w + bv.w;
  v0 = v0 > 0.f ? v0 : (expf(v0) - 1.f);
  v1 = v1 > 0.f ? v1 : (expf(v1) - 1.f);
  v2 = v2 > 0.f ? v2 : (expf(v2) - 1.f);
  v3 = v3 > 0.f ? v3 : (expf(v3) - 1.f);

  // fused projection: g[dst] = elu_h2 @ W2  (lane's 4 channels -> 10 partials)
  const float* wr = W2 + (size_t)(lane * 4) * 10;
  float p[10];
#pragma unroll
  for (int c = 0; c < 10; c++)
    p[c] = v0 * wr[c] + v1 * wr[10 + c] + v2 * wr[20 + c] + v3 * wr[30 + c];
#pragma unroll
  for (int off = 1; off < 64; off <<= 1) {
#pragma unroll
    for (int c = 0; c < 10; c++) p[c] += __shfl_xor(p[c], off, 64);
  }
  if (lane < 10) g[(size_t)dst * 10 + lane] = p[lane];
  if (lane == 0) {
    float ss = 0.f, dd = 0.f;
#pragma unroll
    for (int c = 0; c < 10; c++) {
      ss += p[c] * a_src2[c];
      dd += p[c] * a_dst2[c];
    }
    as2[dst] = ss;
    ad2[dst] = dd;
  }
}

// ---- layer-2 fused softmax + aggregate + bias: 16-lane group per dst ----
__global__ __launch_bounds__(256) void agg2_kernel(
    const int* __restrict__ row_start, const int* __restrict__ csr,
    const float* __restrict__ as2, const float* __restrict__ ad2,
    const float* __restrict__ g, const float* __restrict__ b2,
    float* __restrict__ out, int N) {
  int dst = (int)((blockIdx.x * (size_t)blockDim.x + threadIdx.x) >> 4);
  int l = threadIdx.x & 15;
  if (dst >= N) return;
  const int beg = row_start[dst];
  const int deg = row_start[dst + 1] - beg;
  const float ad = ad2[dst];
  float m = -INFINITY;
  for (int j = l; j < deg; j += 16)
    m = fmaxf(m, lrelu(as2[csr[beg + j]] + ad));
#pragma unroll
  for (int off = 1; off < 16; off <<= 1) m = fmaxf(m, __shfl_xor(m, off, 16));
  float s = 0.f;
  float acc[10] = {};
  for (int j = l; j < deg; j += 16) {
    int src = csr[beg + j];
    float w = expf(lrelu(as2[src] + ad) - m);
    s += w;
    const float2* gp = (const float2*)&g[(size_t)src * 10];
#pragma unroll
    for (int q = 0; q < 5; q++) {
      float2 gv = gp[q];
      acc[2 * q + 0] += w * gv.x;
      acc[2 * q + 1] += w * gv.y;
    }
  }
#pragma unroll
  for (int off = 1; off < 16; off <<= 1) {
    s += __shfl_xor(s, off, 16);
#pragma unroll
    for (int c = 0; c < 10; c++) acc[c] += __shfl_xor(acc[c], off, 16);
  }
  const float inv = 1.f / (s + 1e-16f);
  if (l < 10) out[(size_t)dst * 10 + l] = acc[l] * inv + b2[l];
}

extern "C" void kernel_launch(void* const* d_in, const int* in_sizes, int n_in,
                              void* d_out, int out_size, void* d_ws,
                              size_t ws_size, hipStream_t stream) {
  const float* x      = (const float*)d_in[0];
  const int*   ei     = (const int*)d_in[1];
  const float* W1     = (const float*)d_in[2];
  const float* a_src1 = (const float*)d_in[3];
  const float* a_dst1 = (const float*)d_in[4];
  const float* b1     = (const float*)d_in[5];
  const float* W2     = (const float*)d_in[6];
  const float* a_src2 = (const float*)d_in[7];
  const float* a_dst2 = (const float*)d_in[8];
  const float* b2     = (const float*)d_in[9];
  float* out = (float*)d_out;

  const int N = in_sizes[0] / 128;   // 50000
  const int E = in_sizes[1] / 2;     // 800000

  float* ws = (float*)d_ws;
  float* h1  = ws;                                 // N*256 f32
  unsigned short* h1b = (unsigned short*)(h1 + (size_t)N * 256);  // N*256 bf16
  float* as1 = (float*)(h1b + (size_t)N * 256);    // N*8
  float* ad1 = as1 + (size_t)N * 8;                // N*8
  float* g   = ad1 + (size_t)N * 8;                // N*10
  float* as2 = g + (size_t)N * 10;                 // N
  float* ad2 = as2 + N;                            // N
  int* cursor    = (int*)(ad2 + N);                // N (deg, then cursor)
  int* row_start = cursor + N;                     // N+1
  int* csr       = row_start + N + 1;              // E+N

  hipMemsetAsync(cursor, 0, (size_t)N * 4, stream);

  // ---- CSR build (shared by both layers) ----
  deg_kernel<<<(E + 255) / 256, 256, 0, stream>>>(ei, E, cursor);
  scan_kernel<<<1, 1024, 0, stream>>>(cursor, row_start, csr, N);
  scatter_kernel<<<(E + 255) / 256, 256, 0, stream>>>(ei, E, cursor, csr);

  // ---- layer 1 projection + logits ----
  dim3 g1((N + BM - 1) / BM, 256 / BN);
  gemm1_kernel<<<g1, 256, 0, stream>>>(x, W1, h1, h1b, N, 256, 128);
  alpha1_kernel<<<(N * 8 + 255) / 256, 256, 0, stream>>>(h1, a_src1, a_dst1,
                                                         as1, ad1, N);

  // ---- fused layer-1 aggregate + ELU + layer-2 projection ----
  agg1_kernel<<<(N + 3) / 4, 256, 0, stream>>>(row_start, csr, as1, ad1, h1b,
                                               b1, W2, a_src2, a_dst2, g, as2,
                                               ad2, N);

  // ---- layer-2 aggregate ----
  agg2_kernel<<<(N * 16 + 255) / 256, 256, 0, stream>>>(row_start, csr, as2,
                                                        ad2, g, b2, out, N);
}

// Round 4
// 418.168 us; speedup vs baseline: 7.6770x; 1.1410x over previous
//
#include <hip/hip_runtime.h>
#include <math.h>

#define NEG_SLOPE 0.2f

typedef unsigned short ushort8_t __attribute__((ext_vector_type(8)));

static __device__ __forceinline__ float lrelu(float v) {
  return v >= 0.f ? v : NEG_SLOPE * v;
}
static __device__ __forceinline__ unsigned short f2bf(float f) {
  unsigned u = __float_as_uint(f);
  u = u + 0x7FFFu + ((u >> 16) & 1u);  // RNE
  return (unsigned short)(u >> 16);
}
static __device__ __forceinline__ float bf2f(unsigned short b) {
  return __uint_as_float(((unsigned)b) << 16);
}

// ---- GEMM1: h1b(bf16) = x @ W1, fused as1/ad1 logits (exact f32) ----
// block: 256 threads, tile 64 rows x 256 cols (full row), 8x8 per thread
#define BM 64
#define BK 16
__global__ __launch_bounds__(256) void gemm1_kernel(
    const float* __restrict__ A, const float* __restrict__ B,
    unsigned short* __restrict__ Cb, const float* __restrict__ a_src,
    const float* __restrict__ a_dst, float* __restrict__ as1,
    float* __restrict__ ad1, int M) {
  __shared__ float As[BK][68];
  __shared__ float Bs[BK][260];
  const int bm = blockIdx.x * BM;
  const int tid = threadIdx.x;
  const int tx = tid & 31, ty = tid >> 5;
  float acc[8][8] = {};
  for (int k0 = 0; k0 < 128; k0 += BK) {
    {  // stage A tile (64 x 16), transposed
      int r = tid >> 2, c = (tid & 3) << 2;
      int row = bm + r;
      float4 v = (row < M) ? *(const float4*)&A[(size_t)row * 128 + k0 + c]
                           : make_float4(0.f, 0.f, 0.f, 0.f);
      As[c + 0][r] = v.x; As[c + 1][r] = v.y;
      As[c + 2][r] = v.z; As[c + 3][r] = v.w;
    }
    {  // stage B tile (16 x 256)
      int r = tid >> 4, c0 = (tid & 15) << 2;
#pragma unroll
      for (int q = 0; q < 4; q++) {
        int col = c0 + q * 64;
        *(float4*)&Bs[r][col] = *(const float4*)&B[(size_t)(k0 + r) * 256 + col];
      }
    }
    __syncthreads();
#pragma unroll
    for (int kk = 0; kk < BK; ++kk) {
      float a[8], b[8];
      *(float4*)&a[0] = *(const float4*)&As[kk][ty * 8];
      *(float4*)&a[4] = *(const float4*)&As[kk][ty * 8 + 4];
      *(float4*)&b[0] = *(const float4*)&Bs[kk][tx * 4];
      *(float4*)&b[4] = *(const float4*)&Bs[kk][128 + tx * 4];
#pragma unroll
      for (int i = 0; i < 8; i++)
#pragma unroll
        for (int j = 0; j < 8; j++) acc[i][j] += a[i] * b[j];
    }
    __syncthreads();
  }
  // epilogue: bf16 store + fused attention logits
  const int hA = tx >> 3;        // head of col-group A (0..3); group B: 4+hA
  const int co = (tx & 7) << 2;  // within-head col offset
  float wsA[4], wdA[4], wsB[4], wdB[4];
#pragma unroll
  for (int j = 0; j < 4; j++) {
    wsA[j] = a_src[hA * 32 + co + j];
    wdA[j] = a_dst[hA * 32 + co + j];
    wsB[j] = a_src[(4 + hA) * 32 + co + j];
    wdB[j] = a_dst[(4 + hA) * 32 + co + j];
  }
#pragma unroll
  for (int i = 0; i < 8; i++) {
    int row = bm + ty * 8 + i;
    if (row < M) {  // uniform within each 8-lane shfl group
      ushort4 ua, ub;
      ua.x = f2bf(acc[i][0]); ua.y = f2bf(acc[i][1]);
      ua.z = f2bf(acc[i][2]); ua.w = f2bf(acc[i][3]);
      ub.x = f2bf(acc[i][4]); ub.y = f2bf(acc[i][5]);
      ub.z = f2bf(acc[i][6]); ub.w = f2bf(acc[i][7]);
      *(ushort4*)&Cb[(size_t)row * 256 + tx * 4] = ua;
      *(ushort4*)&Cb[(size_t)row * 256 + 128 + tx * 4] = ub;
      float sA = 0.f, dA = 0.f, sB = 0.f, dB = 0.f;
#pragma unroll
      for (int j = 0; j < 4; j++) {
        sA += acc[i][j] * wsA[j];
        dA += acc[i][j] * wdA[j];
        sB += acc[i][4 + j] * wsB[j];
        dB += acc[i][4 + j] * wdB[j];
      }
#pragma unroll
      for (int off = 1; off < 8; off <<= 1) {
        sA += __shfl_xor(sA, off, 64);
        dA += __shfl_xor(dA, off, 64);
        sB += __shfl_xor(sB, off, 64);
        dB += __shfl_xor(dB, off, 64);
      }
      if ((tx & 7) == 0) {
        as1[row * 8 + hA] = sA;
        as1[row * 8 + 4 + hA] = sB;
        ad1[row * 8 + hA] = dA;
        ad1[row * 8 + 4 + hA] = dB;
      }
    }
  }
}

// ---------------- CSR build ----------------
__global__ void deg_kernel(const int* __restrict__ ei, int E,
                           int* __restrict__ deg) {
  int e = blockIdx.x * blockDim.x + threadIdx.x;
  if (e < E) atomicAdd(&deg[ei[E + e]], 1);
}

__global__ __launch_bounds__(1024) void scan_kernel(
    int* __restrict__ degcur, int* __restrict__ row_start,
    int* __restrict__ csr, int N) {
  __shared__ int part[1024];
  const int t = threadIdx.x;
  const int chunk = (N + 1023) / 1024;
  const int beg = t * chunk;
  const int end = min(beg + chunk, N);
  int sum = 0;
  for (int i = beg; i < end; i++) sum += degcur[i] + 1;
  part[t] = sum;
  __syncthreads();
  for (int off = 1; off < 1024; off <<= 1) {
    int v = (t >= off) ? part[t - off] : 0;
    __syncthreads();
    part[t] += v;
    __syncthreads();
  }
  int p = (t == 0) ? 0 : part[t - 1];
  for (int i = beg; i < end; i++) {
    int d = degcur[i];
    row_start[i] = p;
    csr[p] = i;           // self-loop first
    degcur[i] = p + 1;    // cursor
    p += d + 1;
  }
  if (t == 1023) row_start[N] = part[1023];
}

__global__ void scatter_kernel(const int* __restrict__ ei, int E,
                               int* __restrict__ cursor,
                               int* __restrict__ csr) {
  int e = blockIdx.x * blockDim.x + threadIdx.x;
  if (e < E) {
    int dst = ei[E + e];
    int pos = atomicAdd(&cursor[dst], 1);
    csr[pos] = ei[e];
  }
}

// ---- layer-1 fused: softmax(no-max) + bf16 gather (2 edges/iter) + bias
// ----  + ELU + W2 projection + alpha2 logits.  One wave per dst. ----
__global__ __launch_bounds__(256) void agg1_kernel(
    const int* __restrict__ row_start, const int* __restrict__ csr,
    const float* __restrict__ as1, const float* __restrict__ ad1,
    const unsigned short* __restrict__ h1b, const float* __restrict__ b1,
    const float* __restrict__ W2, const float* __restrict__ a_src2,
    const float* __restrict__ a_dst2, float* __restrict__ g,
    float* __restrict__ as2, float* __restrict__ ad2, int N) {
  int dst = (int)((blockIdx.x * (size_t)blockDim.x + threadIdx.x) >> 6);
  int lane = threadIdx.x & 63;
  if (dst >= N) return;
  const int beg = row_start[dst];
  const int deg = row_start[dst + 1] - beg;

  // phase A: denominator per head (lane hS = lane&7; edge stripe lane>>3)
  const int hS = lane & 7;
  const float adv = ad1[dst * 8 + hS];
  float s = 0.f;
  for (int j = lane >> 3; j < deg; j += 8)
    s += __expf(lrelu(as1[csr[beg + j] * 8 + hS] + adv));
  s += __shfl_xor(s, 8, 64);
  s += __shfl_xor(s, 16, 64);
  s += __shfl_xor(s, 32, 64);

  // phase B: 2 edges in flight; 32 lanes/edge, 8 channels/lane (16B load)
  const int l32 = lane & 31, half = lane >> 5;
  const int hA = l32 >> 2;
  const float adA = __shfl(adv, hA, 64);
  const float invA = 1.f / (__shfl(s, hA, 64) + 1e-16f);
  float acc[8] = {};
  int j = 0;
  for (; j + 2 <= deg; j += 2) {
    int src = csr[beg + j + half];
    float w = __expf(lrelu(as1[src * 8 + hA] + adA)) * invA;
    ushort8_t hv = *(const ushort8_t*)&h1b[(size_t)src * 256 + l32 * 8];
#pragma unroll
    for (int c = 0; c < 8; c++) acc[c] += w * bf2f(hv[c]);
  }
  if (j < deg) {  // odd tail: both halves converge, half 1 contributes 0
    int src = csr[beg + j];
    float w = half ? 0.f : __expf(lrelu(as1[src * 8 + hA] + adA)) * invA;
    ushort8_t hv = *(const ushort8_t*)&h1b[(size_t)src * 256 + l32 * 8];
#pragma unroll
    for (int c = 0; c < 8; c++) acc[c] += w * bf2f(hv[c]);
  }
#pragma unroll
  for (int c = 0; c < 8; c++) acc[c] += __shfl_xor(acc[c], 32, 64);

  // bias + ELU
  float v[8];
#pragma unroll
  for (int c = 0; c < 8; c++) {
    float t = acc[c] + b1[l32 * 8 + c];
    v[c] = t > 0.f ? t : (__expf(t) - 1.f);
  }
  // fused layer-2 projection: p[10] = elu_h2 @ W2
  float p[10];
#pragma unroll
  for (int c = 0; c < 10; c++) p[c] = 0.f;
#pragma unroll
  for (int cc = 0; cc < 8; cc++) {
    const float* wr = W2 + (size_t)(l32 * 8 + cc) * 10;
    float vc = v[cc];
#pragma unroll
    for (int c = 0; c < 10; c++) p[c] += vc * wr[c];
  }
#pragma unroll
  for (int off = 1; off < 32; off <<= 1) {
#pragma unroll
    for (int c = 0; c < 10; c++) p[c] += __shfl_xor(p[c], off, 64);
  }
  if (lane < 10) g[(size_t)dst * 10 + lane] = p[lane];
  if (lane == 0) {
    float ss = 0.f, dd = 0.f;
#pragma unroll
    for (int c = 0; c < 10; c++) {
      ss += p[c] * a_src2[c];
      dd += p[c] * a_dst2[c];
    }
    as2[dst] = ss;
    ad2[dst] = dd;
  }
}

// ---- layer-2: single-pass softmax(no-max) + aggregate, 16 lanes/dst ----
__global__ __launch_bounds__(256) void agg2_kernel(
    const int* __restrict__ row_start, const int* __restrict__ csr,
    const float* __restrict__ as2, const float* __restrict__ ad2,
    const float* __restrict__ g, const float* __restrict__ b2,
    float* __restrict__ out, int N) {
  int dst = (int)((blockIdx.x * (size_t)blockDim.x + threadIdx.x) >> 4);
  int l = threadIdx.x & 15;
  if (dst >= N) return;
  const int beg = row_start[dst];
  const int deg = row_start[dst + 1] - beg;
  const float ad = ad2[dst];
  float s = 0.f;
  float acc[10] = {};
  for (int j = l; j < deg; j += 16) {
    int src = csr[beg + j];
    float w = __expf(lrelu(as2[src] + ad));
    s += w;
    const float2* gp = (const float2*)&g[(size_t)src * 10];
#pragma unroll
    for (int q = 0; q < 5; q++) {
      float2 gv = gp[q];
      acc[2 * q + 0] += w * gv.x;
      acc[2 * q + 1] += w * gv.y;
    }
  }
#pragma unroll
  for (int off = 1; off < 16; off <<= 1) {
    s += __shfl_xor(s, off, 16);
#pragma unroll
    for (int c = 0; c < 10; c++) acc[c] += __shfl_xor(acc[c], off, 16);
  }
  const float inv = 1.f / (s + 1e-16f);
  if (l < 10) out[(size_t)dst * 10 + l] = acc[l] * inv + b2[l];
}

extern "C" void kernel_launch(void* const* d_in, const int* in_sizes, int n_in,
                              void* d_out, int out_size, void* d_ws,
                              size_t ws_size, hipStream_t stream) {
  const float* x      = (const float*)d_in[0];
  const int*   ei     = (const int*)d_in[1];
  const float* W1     = (const float*)d_in[2];
  const float* a_src1 = (const float*)d_in[3];
  const float* a_dst1 = (const float*)d_in[4];
  const float* b1     = (const float*)d_in[5];
  const float* W2     = (const float*)d_in[6];
  const float* a_src2 = (const float*)d_in[7];
  const float* a_dst2 = (const float*)d_in[8];
  const float* b2     = (const float*)d_in[9];
  float* out = (float*)d_out;

  const int N = in_sizes[0] / 128;   // 50000
  const int E = in_sizes[1] / 2;     // 800000

  unsigned short* h1b = (unsigned short*)d_ws;          // N*256 bf16
  float* as1 = (float*)(h1b + (size_t)N * 256);         // N*8
  float* ad1 = as1 + (size_t)N * 8;                     // N*8
  float* g   = ad1 + (size_t)N * 8;                     // N*10
  float* as2 = g + (size_t)N * 10;                      // N
  float* ad2 = as2 + N;                                 // N
  int* cursor    = (int*)(ad2 + N);                     // N (deg, then cursor)
  int* row_start = cursor + N;                          // N+1
  int* csr       = row_start + N + 1;                   // E+N

  hipMemsetAsync(cursor, 0, (size_t)N * 4, stream);

  // ---- CSR build (shared by both layers) ----
  deg_kernel<<<(E + 255) / 256, 256, 0, stream>>>(ei, E, cursor);
  scan_kernel<<<1, 1024, 0, stream>>>(cursor, row_start, csr, N);
  scatter_kernel<<<(E + 255) / 256, 256, 0, stream>>>(ei, E, cursor, csr);

  // ---- layer-1 projection + fused logits ----
  gemm1_kernel<<<(N + BM - 1) / BM, 256, 0, stream>>>(x, W1, h1b, a_src1,
                                                      a_dst1, as1, ad1, N);

  // ---- fused layer-1 aggregate + ELU + layer-2 projection ----
  agg1_kernel<<<(N + 3) / 4, 256, 0, stream>>>(row_start, csr, as1, ad1, h1b,
                                               b1, W2, a_src2, a_dst2, g, as2,
                                               ad2, N);

  // ---- layer-2 aggregate ----
  agg2_kernel<<<(N * 16 + 255) / 256, 256, 0, stream>>>(row_start, csr, as2,
                                                        ad2, g, b2, out, N);
}

// Round 5
// 301.185 us; speedup vs baseline: 10.6589x; 1.3884x over previous
//
#include <hip/hip_runtime.h>
#include <math.h>

#define NEG_SLOPE 0.2f

typedef unsigned short ushort8_t __attribute__((ext_vector_type(8)));

static __device__ __forceinline__ float lrelu(float v) {
  return v >= 0.f ? v : NEG_SLOPE * v;
}
static __device__ __forceinline__ unsigned short f2bf(float f) {
  unsigned u = __float_as_uint(f);
  u = u + 0x7FFFu + ((u >> 16) & 1u);  // RNE
  return (unsigned short)(u >> 16);
}
static __device__ __forceinline__ float bf2f(unsigned short b) {
  return __uint_as_float(((unsigned)b) << 16);
}

// ---- GEMM1: h1b(bf16) = x @ W1, fused as1/ad1 logits (exact f32) ----
// block: 256 threads, tile 64 rows x 256 cols (full row), 8x8 per thread
#define BM 64
#define BK 16
__global__ __launch_bounds__(256) void gemm1_kernel(
    const float* __restrict__ A, const float* __restrict__ B,
    unsigned short* __restrict__ Cb, const float* __restrict__ a_src,
    const float* __restrict__ a_dst, float* __restrict__ as1,
    float* __restrict__ ad1, int M) {
  __shared__ float As[BK][68];
  __shared__ float Bs[BK][260];
  const int bm = blockIdx.x * BM;
  const int tid = threadIdx.x;
  const int tx = tid & 31, ty = tid >> 5;
  float acc[8][8] = {};
  for (int k0 = 0; k0 < 128; k0 += BK) {
    {  // stage A tile (64 x 16), transposed
      int r = tid >> 2, c = (tid & 3) << 2;
      int row = bm + r;
      float4 v = (row < M) ? *(const float4*)&A[(size_t)row * 128 + k0 + c]
                           : make_float4(0.f, 0.f, 0.f, 0.f);
      As[c + 0][r] = v.x; As[c + 1][r] = v.y;
      As[c + 2][r] = v.z; As[c + 3][r] = v.w;
    }
    {  // stage B tile (16 x 256)
      int r = tid >> 4, c0 = (tid & 15) << 2;
#pragma unroll
      for (int q = 0; q < 4; q++) {
        int col = c0 + q * 64;
        *(float4*)&Bs[r][col] = *(const float4*)&B[(size_t)(k0 + r) * 256 + col];
      }
    }
    __syncthreads();
#pragma unroll
    for (int kk = 0; kk < BK; ++kk) {
      float a[8], b[8];
      *(float4*)&a[0] = *(const float4*)&As[kk][ty * 8];
      *(float4*)&a[4] = *(const float4*)&As[kk][ty * 8 + 4];
      *(float4*)&b[0] = *(const float4*)&Bs[kk][tx * 4];
      *(float4*)&b[4] = *(const float4*)&Bs[kk][128 + tx * 4];
#pragma unroll
      for (int i = 0; i < 8; i++)
#pragma unroll
        for (int j = 0; j < 8; j++) acc[i][j] += a[i] * b[j];
    }
    __syncthreads();
  }
  // epilogue: bf16 store + fused attention logits
  const int hA = tx >> 3;        // head of col-group A (0..3); group B: 4+hA
  const int co = (tx & 7) << 2;  // within-head col offset
  float wsA[4], wdA[4], wsB[4], wdB[4];
#pragma unroll
  for (int j = 0; j < 4; j++) {
    wsA[j] = a_src[hA * 32 + co + j];
    wdA[j] = a_dst[hA * 32 + co + j];
    wsB[j] = a_src[(4 + hA) * 32 + co + j];
    wdB[j] = a_dst[(4 + hA) * 32 + co + j];
  }
#pragma unroll
  for (int i = 0; i < 8; i++) {
    int row = bm + ty * 8 + i;
    if (row < M) {  // uniform within each 8-lane shfl group
      ushort4 ua, ub;
      ua.x = f2bf(acc[i][0]); ua.y = f2bf(acc[i][1]);
      ua.z = f2bf(acc[i][2]); ua.w = f2bf(acc[i][3]);
      ub.x = f2bf(acc[i][4]); ub.y = f2bf(acc[i][5]);
      ub.z = f2bf(acc[i][6]); ub.w = f2bf(acc[i][7]);
      *(ushort4*)&Cb[(size_t)row * 256 + tx * 4] = ua;
      *(ushort4*)&Cb[(size_t)row * 256 + 128 + tx * 4] = ub;
      float sA = 0.f, dA = 0.f, sB = 0.f, dB = 0.f;
#pragma unroll
      for (int j = 0; j < 4; j++) {
        sA += acc[i][j] * wsA[j];
        dA += acc[i][j] * wdA[j];
        sB += acc[i][4 + j] * wsB[j];
        dB += acc[i][4 + j] * wdB[j];
      }
#pragma unroll
      for (int off = 1; off < 8; off <<= 1) {
        sA += __shfl_xor(sA, off, 64);
        dA += __shfl_xor(dA, off, 64);
        sB += __shfl_xor(sB, off, 64);
        dB += __shfl_xor(dB, off, 64);
      }
      if ((tx & 7) == 0) {
        as1[row * 8 + hA] = sA;
        as1[row * 8 + 4 + hA] = sB;
        ad1[row * 8 + hA] = dA;
        ad1[row * 8 + 4 + hA] = dB;
      }
    }
  }
}

// ---------------- CSR build ----------------
__global__ void deg_kernel(const int* __restrict__ ei, int E,
                           int* __restrict__ deg) {
  int e = blockIdx.x * blockDim.x + threadIdx.x;
  if (e < E) atomicAdd(&deg[ei[E + e]], 1);
}

// ---- multi-block exclusive scan of (deg+1), SCAN_B nodes per block ----
#define SCAN_B 2048
__global__ __launch_bounds__(256) void scan_p1(const int* __restrict__ deg,
                                               int* __restrict__ blk_sum,
                                               int N) {
  __shared__ int red[256];
  const int t = threadIdx.x;
  const int base = blockIdx.x * SCAN_B;
  int sum = 0;
#pragma unroll
  for (int i = 0; i < SCAN_B / 256; i++) {
    int idx = base + t + i * 256;
    if (idx < N) sum += deg[idx] + 1;
  }
  red[t] = sum;
  __syncthreads();
  for (int off = 128; off > 0; off >>= 1) {
    if (t < off) red[t] += red[t + off];
    __syncthreads();
  }
  if (t == 0) blk_sum[blockIdx.x] = red[0];
}

// single wave: exclusive scan of block sums (nb <= 64), writes total
__global__ __launch_bounds__(64) void scan_p2(int* __restrict__ blk,
                                              int nb,
                                              int* __restrict__ row_start,
                                              int N) {
  int t = threadIdx.x;
  int v = (t < nb) ? blk[t] : 0;
  int inc = v;
#pragma unroll
  for (int off = 1; off < 64; off <<= 1) {
    int u = __shfl_up(inc, off, 64);
    if (t >= off) inc += u;
  }
  if (t < nb) blk[t] = inc - v;  // exclusive offset
  if (t == 63) row_start[N] = inc;  // grand total
}

// per-block local scan + emit row_start, self-loop, cursor
__global__ __launch_bounds__(256) void scan_p3(
    const int* __restrict__ deg, const int* __restrict__ blk_off,
    int* __restrict__ row_start, int* __restrict__ csr,
    int* __restrict__ cursor, int N) {
  __shared__ int tsum[256];
  const int t = threadIdx.x;
  const int base = blockIdx.x * SCAN_B + t * (SCAN_B / 256);
  int v[SCAN_B / 256];
  int s = 0;
#pragma unroll
  for (int i = 0; i < SCAN_B / 256; i++) {
    int idx = base + i;
    v[i] = s;  // local exclusive prefix
    if (idx < N) s += deg[idx] + 1;
  }
  tsum[t] = s;
  __syncthreads();
  for (int off = 1; off < 256; off <<= 1) {
    int x = (t >= off) ? tsum[t - off] : 0;
    __syncthreads();
    tsum[t] += x;
    __syncthreads();
  }
  const int offv = blk_off[blockIdx.x] + ((t == 0) ? 0 : tsum[t - 1]);
#pragma unroll
  for (int i = 0; i < SCAN_B / 256; i++) {
    int idx = base + i;
    if (idx < N) {
      int p = offv + v[i];
      row_start[idx] = p;
      csr[p] = idx;       // self-loop first
      cursor[idx] = p + 1;
    }
  }
}

__global__ void scatter_kernel(const int* __restrict__ ei, int E,
                               int* __restrict__ cursor,
                               int* __restrict__ csr) {
  int e = blockIdx.x * blockDim.x + threadIdx.x;
  if (e < E) {
    int dst = ei[E + e];
    int pos = atomicAdd(&cursor[dst], 1);
    csr[pos] = ei[e];
  }
}

// ---- layer-1 fused: softmax(no-max) + bf16 gather (2 edges/iter) + bias
// ----  + ELU + W2 projection + alpha2 logits.  One wave per dst. ----
__global__ __launch_bounds__(256) void agg1_kernel(
    const int* __restrict__ row_start, const int* __restrict__ csr,
    const float* __restrict__ as1, const float* __restrict__ ad1,
    const unsigned short* __restrict__ h1b, const float* __restrict__ b1,
    const float* __restrict__ W2, const float* __restrict__ a_src2,
    const float* __restrict__ a_dst2, float* __restrict__ g,
    float* __restrict__ as2, float* __restrict__ ad2, int N) {
  int dst = (int)((blockIdx.x * (size_t)blockDim.x + threadIdx.x) >> 6);
  int lane = threadIdx.x & 63;
  if (dst >= N) return;
  const int beg = row_start[dst];
  const int deg = row_start[dst + 1] - beg;

  // phase A: denominator per head (lane hS = lane&7; edge stripe lane>>3)
  const int hS = lane & 7;
  const float adv = ad1[dst * 8 + hS];
  float s = 0.f;
  for (int j = lane >> 3; j < deg; j += 8)
    s += __expf(lrelu(as1[csr[beg + j] * 8 + hS] + adv));
  s += __shfl_xor(s, 8, 64);
  s += __shfl_xor(s, 16, 64);
  s += __shfl_xor(s, 32, 64);

  // phase B: 2 edges in flight; 32 lanes/edge, 8 channels/lane (16B load)
  const int l32 = lane & 31, half = lane >> 5;
  const int hA = l32 >> 2;
  const float adA = __shfl(adv, hA, 64);
  const float invA = 1.f / (__shfl(s, hA, 64) + 1e-16f);
  float acc[8] = {};
  int j = 0;
  for (; j + 2 <= deg; j += 2) {
    int src = csr[beg + j + half];
    float w = __expf(lrelu(as1[src * 8 + hA] + adA)) * invA;
    ushort8_t hv = *(const ushort8_t*)&h1b[(size_t)src * 256 + l32 * 8];
#pragma unroll
    for (int c = 0; c < 8; c++) acc[c] += w * bf2f(hv[c]);
  }
  if (j < deg) {  // odd tail: both halves converge, half 1 contributes 0
    int src = csr[beg + j];
    float w = half ? 0.f : __expf(lrelu(as1[src * 8 + hA] + adA)) * invA;
    ushort8_t hv = *(const ushort8_t*)&h1b[(size_t)src * 256 + l32 * 8];
#pragma unroll
    for (int c = 0; c < 8; c++) acc[c] += w * bf2f(hv[c]);
  }
#pragma unroll
  for (int c = 0; c < 8; c++) acc[c] += __shfl_xor(acc[c], 32, 64);

  // bias + ELU
  float v[8];
#pragma unroll
  for (int c = 0; c < 8; c++) {
    float t = acc[c] + b1[l32 * 8 + c];
    v[c] = t > 0.f ? t : (__expf(t) - 1.f);
  }
  // fused layer-2 projection: p[10] = elu_h2 @ W2
  float p[10];
#pragma unroll
  for (int c = 0; c < 10; c++) p[c] = 0.f;
#pragma unroll
  for (int cc = 0; cc < 8; cc++) {
    const float* wr = W2 + (size_t)(l32 * 8 + cc) * 10;
    float vc = v[cc];
#pragma unroll
    for (int c = 0; c < 10; c++) p[c] += vc * wr[c];
  }
#pragma unroll
  for (int off = 1; off < 32; off <<= 1) {
#pragma unroll
    for (int c = 0; c < 10; c++) p[c] += __shfl_xor(p[c], off, 64);
  }
  if (lane < 10) g[(size_t)dst * 10 + lane] = p[lane];
  if (lane == 0) {
    float ss = 0.f, dd = 0.f;
#pragma unroll
    for (int c = 0; c < 10; c++) {
      ss += p[c] * a_src2[c];
      dd += p[c] * a_dst2[c];
    }
    as2[dst] = ss;
    ad2[dst] = dd;
  }
}

// ---- layer-2: single-pass softmax(no-max) + aggregate, 16 lanes/dst ----
__global__ __launch_bounds__(256) void agg2_kernel(
    const int* __restrict__ row_start, const int* __restrict__ csr,
    const float* __restrict__ as2, const float* __restrict__ ad2,
    const float* __restrict__ g, const float* __restrict__ b2,
    float* __restrict__ out, int N) {
  int dst = (int)((blockIdx.x * (size_t)blockDim.x + threadIdx.x) >> 4);
  int l = threadIdx.x & 15;
  if (dst >= N) return;
  const int beg = row_start[dst];
  const int deg = row_start[dst + 1] - beg;
  const float ad = ad2[dst];
  float s = 0.f;
  float acc[10] = {};
  for (int j = l; j < deg; j += 16) {
    int src = csr[beg + j];
    float w = __expf(lrelu(as2[src] + ad));
    s += w;
    const float2* gp = (const float2*)&g[(size_t)src * 10];
#pragma unroll
    for (int q = 0; q < 5; q++) {
      float2 gv = gp[q];
      acc[2 * q + 0] += w * gv.x;
      acc[2 * q + 1] += w * gv.y;
    }
  }
#pragma unroll
  for (int off = 1; off < 16; off <<= 1) {
    s += __shfl_xor(s, off, 16);
#pragma unroll
    for (int c = 0; c < 10; c++) acc[c] += __shfl_xor(acc[c], off, 16);
  }
  const float inv = 1.f / (s + 1e-16f);
  if (l < 10) out[(size_t)dst * 10 + l] = acc[l] * inv + b2[l];
}

extern "C" void kernel_launch(void* const* d_in, const int* in_sizes, int n_in,
                              void* d_out, int out_size, void* d_ws,
                              size_t ws_size, hipStream_t stream) {
  const float* x      = (const float*)d_in[0];
  const int*   ei     = (const int*)d_in[1];
  const float* W1     = (const float*)d_in[2];
  const float* a_src1 = (const float*)d_in[3];
  const float* a_dst1 = (const float*)d_in[4];
  const float* b1     = (const float*)d_in[5];
  const float* W2     = (const float*)d_in[6];
  const float* a_src2 = (const float*)d_in[7];
  const float* a_dst2 = (const float*)d_in[8];
  const float* b2     = (const float*)d_in[9];
  float* out = (float*)d_out;

  const int N = in_sizes[0] / 128;   // 50000
  const int E = in_sizes[1] / 2;     // 800000
  const int nb = (N + SCAN_B - 1) / SCAN_B;  // 25

  unsigned short* h1b = (unsigned short*)d_ws;          // N*256 bf16
  float* as1 = (float*)(h1b + (size_t)N * 256);         // N*8
  float* ad1 = as1 + (size_t)N * 8;                     // N*8
  float* g   = ad1 + (size_t)N * 8;                     // N*10
  float* as2 = g + (size_t)N * 10;                      // N
  float* ad2 = as2 + N;                                 // N
  int* cursor    = (int*)(ad2 + N);                     // N (deg, then cursor)
  int* row_start = cursor + N;                          // N+1
  int* blk_sum   = row_start + N + 1;                   // nb
  int* csr       = blk_sum + 64;                        // E+N

  hipMemsetAsync(cursor, 0, (size_t)N * 4, stream);

  // ---- CSR build (shared by both layers) ----
  deg_kernel<<<(E + 255) / 256, 256, 0, stream>>>(ei, E, cursor);
  scan_p1<<<nb, 256, 0, stream>>>(cursor, blk_sum, N);
  scan_p2<<<1, 64, 0, stream>>>(blk_sum, nb, row_start, N);
  scan_p3<<<nb, 256, 0, stream>>>(cursor, blk_sum, row_start, csr, cursor, N);
  scatter_kernel<<<(E + 255) / 256, 256, 0, stream>>>(ei, E, cursor, csr);

  // ---- layer-1 projection + fused logits ----
  gemm1_kernel<<<(N + BM - 1) / BM, 256, 0, stream>>>(x, W1, h1b, a_src1,
                                                      a_dst1, as1, ad1, N);

  // ---- fused layer-1 aggregate + ELU + layer-2 projection ----
  agg1_kernel<<<(N + 3) / 4, 256, 0, stream>>>(row_start, csr, as1, ad1, h1b,
                                               b1, W2, a_src2, a_dst2, g, as2,
                                               ad2, N);

  // ---- layer-2 aggregate ----
  agg2_kernel<<<(N * 16 + 255) / 256, 256, 0, stream>>>(row_start, csr, as2,
                                                        ad2, g, b2, out, N);
}

// Round 6
// 284.337 us; speedup vs baseline: 11.2905x; 1.0593x over previous
//
#include <hip/hip_runtime.h>
#include <math.h>

#define NEG_SLOPE 0.2f
#define INV_LN2 1.44269504088896f

typedef unsigned short ushort8_t __attribute__((ext_vector_type(8)));

static __device__ __forceinline__ float lrelu(float v) {
  return v >= 0.f ? v : NEG_SLOPE * v;
}
static __device__ __forceinline__ unsigned short f2bf(float f) {
  unsigned u = __float_as_uint(f);
  u = u + 0x7FFFu + ((u >> 16) & 1u);  // RNE
  return (unsigned short)(u >> 16);
}
static __device__ __forceinline__ float bf2f(unsigned short b) {
  return __uint_as_float(((unsigned)b) << 16);
}
static __device__ __forceinline__ float exp2fast(float x) {
  return __builtin_amdgcn_exp2f(x);
}

// ---- GEMM1: h1b(bf16) = x @ W1, fused as1/ad1 logits (f32, pre-scaled by
// ---- 1/ln2 so downstream softmax uses exp2).  64x256 tile, 8x8/thread. ----
#define BM 64
#define BK 16
__global__ __launch_bounds__(256) void gemm1_kernel(
    const float* __restrict__ A, const float* __restrict__ B,
    unsigned short* __restrict__ Cb, const float* __restrict__ a_src,
    const float* __restrict__ a_dst, float* __restrict__ as1,
    float* __restrict__ ad1, int M) {
  __shared__ float As[BK][68];
  __shared__ float Bs[BK][260];
  const int bm = blockIdx.x * BM;
  const int tid = threadIdx.x;
  const int tx = tid & 31, ty = tid >> 5;
  float acc[8][8] = {};
  for (int k0 = 0; k0 < 128; k0 += BK) {
    {  // stage A tile (64 x 16), transposed
      int r = tid >> 2, c = (tid & 3) << 2;
      int row = bm + r;
      float4 v = (row < M) ? *(const float4*)&A[(size_t)row * 128 + k0 + c]
                           : make_float4(0.f, 0.f, 0.f, 0.f);
      As[c + 0][r] = v.x; As[c + 1][r] = v.y;
      As[c + 2][r] = v.z; As[c + 3][r] = v.w;
    }
    {  // stage B tile (16 x 256)
      int r = tid >> 4, c0 = (tid & 15) << 2;
#pragma unroll
      for (int q = 0; q < 4; q++) {
        int col = c0 + q * 64;
        *(float4*)&Bs[r][col] = *(const float4*)&B[(size_t)(k0 + r) * 256 + col];
      }
    }
    __syncthreads();
#pragma unroll
    for (int kk = 0; kk < BK; ++kk) {
      float a[8], b[8];
      *(float4*)&a[0] = *(const float4*)&As[kk][ty * 8];
      *(float4*)&a[4] = *(const float4*)&As[kk][ty * 8 + 4];
      *(float4*)&b[0] = *(const float4*)&Bs[kk][tx * 4];
      *(float4*)&b[4] = *(const float4*)&Bs[kk][128 + tx * 4];
#pragma unroll
      for (int i = 0; i < 8; i++)
#pragma unroll
        for (int j = 0; j < 8; j++) acc[i][j] += a[i] * b[j];
    }
    __syncthreads();
  }
  // epilogue: bf16 store + fused attention logits (scaled by 1/ln2)
  const int hA = tx >> 3;        // head of col-group A (0..3); group B: 4+hA
  const int co = (tx & 7) << 2;  // within-head col offset
  float wsA[4], wdA[4], wsB[4], wdB[4];
#pragma unroll
  for (int j = 0; j < 4; j++) {
    wsA[j] = a_src[hA * 32 + co + j];
    wdA[j] = a_dst[hA * 32 + co + j];
    wsB[j] = a_src[(4 + hA) * 32 + co + j];
    wdB[j] = a_dst[(4 + hA) * 32 + co + j];
  }
#pragma unroll
  for (int i = 0; i < 8; i++) {
    int row = bm + ty * 8 + i;
    if (row < M) {  // uniform within each 8-lane shfl group
      ushort4 ua, ub;
      ua.x = f2bf(acc[i][0]); ua.y = f2bf(acc[i][1]);
      ua.z = f2bf(acc[i][2]); ua.w = f2bf(acc[i][3]);
      ub.x = f2bf(acc[i][4]); ub.y = f2bf(acc[i][5]);
      ub.z = f2bf(acc[i][6]); ub.w = f2bf(acc[i][7]);
      *(ushort4*)&Cb[(size_t)row * 256 + tx * 4] = ua;
      *(ushort4*)&Cb[(size_t)row * 256 + 128 + tx * 4] = ub;
      float sA = 0.f, dA = 0.f, sB = 0.f, dB = 0.f;
#pragma unroll
      for (int j = 0; j < 4; j++) {
        sA += acc[i][j] * wsA[j];
        dA += acc[i][j] * wdA[j];
        sB += acc[i][4 + j] * wsB[j];
        dB += acc[i][4 + j] * wdB[j];
      }
#pragma unroll
      for (int off = 1; off < 8; off <<= 1) {
        sA += __shfl_xor(sA, off, 64);
        dA += __shfl_xor(dA, off, 64);
        sB += __shfl_xor(sB, off, 64);
        dB += __shfl_xor(dB, off, 64);
      }
      if ((tx & 7) == 0) {
        as1[row * 8 + hA] = sA * INV_LN2;
        as1[row * 8 + 4 + hA] = sB * INV_LN2;
        ad1[row * 8 + hA] = dA * INV_LN2;
        ad1[row * 8 + 4 + hA] = dB * INV_LN2;
      }
    }
  }
}

// ---------------- CSR build ----------------
__global__ void deg_kernel(const int* __restrict__ ei, int E,
                           int* __restrict__ deg) {
  int e = blockIdx.x * blockDim.x + threadIdx.x;
  if (e < E) atomicAdd(&deg[ei[E + e]], 1);
}

// ---- multi-block exclusive scan of (deg+1), SCAN_B nodes per block ----
#define SCAN_B 2048
__global__ __launch_bounds__(256) void scan_p1(const int* __restrict__ deg,
                                               int* __restrict__ blk_sum,
                                               int N) {
  __shared__ int red[256];
  const int t = threadIdx.x;
  const int base = blockIdx.x * SCAN_B;
  int sum = 0;
#pragma unroll
  for (int i = 0; i < SCAN_B / 256; i++) {
    int idx = base + t + i * 256;
    if (idx < N) sum += deg[idx] + 1;
  }
  red[t] = sum;
  __syncthreads();
  for (int off = 128; off > 0; off >>= 1) {
    if (t < off) red[t] += red[t + off];
    __syncthreads();
  }
  if (t == 0) blk_sum[blockIdx.x] = red[0];
}

// single wave: exclusive scan of block sums (nb <= 64), writes total
__global__ __launch_bounds__(64) void scan_p2(int* __restrict__ blk,
                                              int nb,
                                              int* __restrict__ row_start,
                                              int N) {
  int t = threadIdx.x;
  int v = (t < nb) ? blk[t] : 0;
  int inc = v;
#pragma unroll
  for (int off = 1; off < 64; off <<= 1) {
    int u = __shfl_up(inc, off, 64);
    if (t >= off) inc += u;
  }
  if (t < nb) blk[t] = inc - v;  // exclusive offset
  if (t == 63) row_start[N] = inc;  // grand total
}

// per-block local scan + emit row_start, self-loop, cursor
__global__ __launch_bounds__(256) void scan_p3(
    const int* __restrict__ deg, const int* __restrict__ blk_off,
    int* __restrict__ row_start, int* __restrict__ csr,
    int* __restrict__ cursor, int N) {
  __shared__ int tsum[256];
  const int t = threadIdx.x;
  const int base = blockIdx.x * SCAN_B + t * (SCAN_B / 256);
  int v[SCAN_B / 256];
  int s = 0;
#pragma unroll
  for (int i = 0; i < SCAN_B / 256; i++) {
    int idx = base + i;
    v[i] = s;  // local exclusive prefix
    if (idx < N) s += deg[idx] + 1;
  }
  tsum[t] = s;
  __syncthreads();
  for (int off = 1; off < 256; off <<= 1) {
    int x = (t >= off) ? tsum[t - off] : 0;
    __syncthreads();
    tsum[t] += x;
    __syncthreads();
  }
  const int offv = blk_off[blockIdx.x] + ((t == 0) ? 0 : tsum[t - 1]);
#pragma unroll
  for (int i = 0; i < SCAN_B / 256; i++) {
    int idx = base + i;
    if (idx < N) {
      int p = offv + v[i];
      row_start[idx] = p;
      csr[p] = idx;       // self-loop first
      cursor[idx] = p + 1;
    }
  }
}

__global__ void scatter_kernel(const int* __restrict__ ei, int E,
                               int* __restrict__ cursor,
                               int* __restrict__ csr) {
  int e = blockIdx.x * blockDim.x + threadIdx.x;
  if (e < E) {
    int dst = ei[E + e];
    int pos = atomicAdd(&cursor[dst], 1);
    csr[pos] = ei[e];
  }
}

// ---- layer-1 fused: SINGLE-PASS softmax+aggregate (denominator merged),
// ---- software-pipelined bf16 gather (2 edges/iter, prefetch), + bias +
// ---- ELU + W2 projection + alpha2 logits.  One wave per dst. ----
__global__ __launch_bounds__(256) void agg1_kernel(
    const int* __restrict__ row_start, const int* __restrict__ csr,
    const float* __restrict__ as1, const float* __restrict__ ad1,
    const unsigned short* __restrict__ h1b, const float* __restrict__ b1,
    const float* __restrict__ W2, const float* __restrict__ a_src2,
    const float* __restrict__ a_dst2, float* __restrict__ g,
    float* __restrict__ as2, float* __restrict__ ad2, int N) {
  int dst = (int)((blockIdx.x * (size_t)blockDim.x + threadIdx.x) >> 6);
  int lane = threadIdx.x & 63;
  if (dst >= N) return;
  const int beg = row_start[dst];
  const int deg = row_start[dst + 1] - beg;

  // 32 lanes per edge, 2 edges (halves) in flight; lane owns 8 channels
  const int l32 = lane & 31, half = lane >> 5;
  const int hA = l32 >> 2;  // head 0..7
  const float adA = ad1[dst * 8 + hA];  // pre-scaled by 1/ln2

  float acc[8] = {};
  float s = 0.f;

  // prologue: prefetch pair 0
  int jj0 = half < deg ? half : deg - 1;
  int src_n = csr[beg + jj0];
  float e_n = as1[src_n * 8 + hA];
  ushort8_t hv_n = *(const ushort8_t*)&h1b[(size_t)src_n * 256 + l32 * 8];

#pragma unroll 2
  for (int j = 0; j < deg; j += 2) {
    const float e_c = e_n;
    const ushort8_t hv_c = hv_n;
    const bool valid = (j + half) < deg;
    if (j + 2 < deg) {  // prefetch next pair
      int jn = j + 2 + half;
      if (jn > deg - 1) jn = deg - 1;
      src_n = csr[beg + jn];
      e_n = as1[src_n * 8 + hA];
      hv_n = *(const ushort8_t*)&h1b[(size_t)src_n * 256 + l32 * 8];
    }
    float w = valid ? exp2fast(lrelu(e_c + adA)) : 0.f;
    s += w;
#pragma unroll
    for (int c = 0; c < 8; c++) acc[c] += w * bf2f(hv_c[c]);
  }
  // combine the two halves
  s += __shfl_xor(s, 32, 64);
#pragma unroll
  for (int c = 0; c < 8; c++) acc[c] += __shfl_xor(acc[c], 32, 64);
  const float inv = 1.f / (s + 1e-16f);

  // normalize + bias + ELU
  float v[8];
#pragma unroll
  for (int c = 0; c < 8; c++) {
    float t = acc[c] * inv + b1[l32 * 8 + c];
    v[c] = t > 0.f ? t : (__expf(t) - 1.f);
  }
  // fused layer-2 projection: p[10] = elu_h2 @ W2
  float p[10];
#pragma unroll
  for (int c = 0; c < 10; c++) p[c] = 0.f;
#pragma unroll
  for (int cc = 0; cc < 8; cc++) {
    const float* wr = W2 + (size_t)(l32 * 8 + cc) * 10;
    float vc = v[cc];
#pragma unroll
    for (int c = 0; c < 10; c++) p[c] += vc * wr[c];
  }
#pragma unroll
  for (int off = 1; off < 32; off <<= 1) {
#pragma unroll
    for (int c = 0; c < 10; c++) p[c] += __shfl_xor(p[c], off, 64);
  }
  if (lane < 10) g[(size_t)dst * 10 + lane] = p[lane];
  if (lane == 0) {
    float ss = 0.f, dd = 0.f;
#pragma unroll
    for (int c = 0; c < 10; c++) {
      ss += p[c] * a_src2[c];
      dd += p[c] * a_dst2[c];
    }
    as2[dst] = ss * INV_LN2;  // pre-scaled for exp2 in agg2
    ad2[dst] = dd * INV_LN2;
  }
}

// ---- layer-2: single-pass softmax(no-max,exp2) + aggregate, 16 lanes/dst ----
__global__ __launch_bounds__(256) void agg2_kernel(
    const int* __restrict__ row_start, const int* __restrict__ csr,
    const float* __restrict__ as2, const float* __restrict__ ad2,
    const float* __restrict__ g, const float* __restrict__ b2,
    float* __restrict__ out, int N) {
  int dst = (int)((blockIdx.x * (size_t)blockDim.x + threadIdx.x) >> 4);
  int l = threadIdx.x & 15;
  if (dst >= N) return;
  const int beg = row_start[dst];
  const int deg = row_start[dst + 1] - beg;
  const float ad = ad2[dst];
  float s = 0.f;
  float acc[10] = {};
  for (int j = l; j < deg; j += 16) {
    int src = csr[beg + j];
    float w = exp2fast(lrelu(as2[src] + ad));
    s += w;
    const float2* gp = (const float2*)&g[(size_t)src * 10];
#pragma unroll
    for (int q = 0; q < 5; q++) {
      float2 gv = gp[q];
      acc[2 * q + 0] += w * gv.x;
      acc[2 * q + 1] += w * gv.y;
    }
  }
#pragma unroll
  for (int off = 1; off < 16; off <<= 1) {
    s += __shfl_xor(s, off, 16);
#pragma unroll
    for (int c = 0; c < 10; c++) acc[c] += __shfl_xor(acc[c], off, 16);
  }
  const float inv = 1.f / (s + 1e-16f);
  if (l < 10) out[(size_t)dst * 10 + l] = acc[l] * inv + b2[l];
}

extern "C" void kernel_launch(void* const* d_in, const int* in_sizes, int n_in,
                              void* d_out, int out_size, void* d_ws,
                              size_t ws_size, hipStream_t stream) {
  const float* x      = (const float*)d_in[0];
  const int*   ei     = (const int*)d_in[1];
  const float* W1     = (const float*)d_in[2];
  const float* a_src1 = (const float*)d_in[3];
  const float* a_dst1 = (const float*)d_in[4];
  const float* b1     = (const float*)d_in[5];
  const float* W2     = (const float*)d_in[6];
  const float* a_src2 = (const float*)d_in[7];
  const float* a_dst2 = (const float*)d_in[8];
  const float* b2     = (const float*)d_in[9];
  float* out = (float*)d_out;

  const int N = in_sizes[0] / 128;   // 50000
  const int E = in_sizes[1] / 2;     // 800000
  const int nb = (N + SCAN_B - 1) / SCAN_B;  // 25

  unsigned short* h1b = (unsigned short*)d_ws;          // N*256 bf16
  float* as1 = (float*)(h1b + (size_t)N * 256);         // N*8
  float* ad1 = as1 + (size_t)N * 8;                     // N*8
  float* g   = ad1 + (size_t)N * 8;                     // N*10
  float* as2 = g + (size_t)N * 10;                      // N
  float* ad2 = as2 + N;                                 // N
  int* cursor    = (int*)(ad2 + N);                     // N (deg, then cursor)
  int* row_start = cursor + N;                          // N+1
  int* blk_sum   = row_start + N + 1;                   // nb (padded to 64)
  int* csr       = blk_sum + 64;                        // E+N

  hipMemsetAsync(cursor, 0, (size_t)N * 4, stream);

  // ---- CSR build (shared by both layers) ----
  deg_kernel<<<(E + 255) / 256, 256, 0, stream>>>(ei, E, cursor);
  scan_p1<<<nb, 256, 0, stream>>>(cursor, blk_sum, N);
  scan_p2<<<1, 64, 0, stream>>>(blk_sum, nb, row_start, N);
  scan_p3<<<nb, 256, 0, stream>>>(cursor, blk_sum, row_start, csr, cursor, N);
  scatter_kernel<<<(E + 255) / 256, 256, 0, stream>>>(ei, E, cursor, csr);

  // ---- layer-1 projection + fused logits ----
  gemm1_kernel<<<(N + BM - 1) / BM, 256, 0, stream>>>(x, W1, h1b, a_src1,
                                                      a_dst1, as1, ad1, N);

  // ---- fused layer-1 aggregate + ELU + layer-2 projection ----
  agg1_kernel<<<(N + 3) / 4, 256, 0, stream>>>(row_start, csr, as1, ad1, h1b,
                                               b1, W2, a_src2, a_dst2, g, as2,
                                               ad2, N);

  // ---- layer-2 aggregate ----
  agg2_kernel<<<(N * 16 + 255) / 256, 256, 0, stream>>>(row_start, csr, as2,
                                                        ad2, g, b2, out, N);
}

// Round 7
// 278.955 us; speedup vs baseline: 11.5083x; 1.0193x over previous
//
#include <hip/hip_runtime.h>
#include <math.h>

#define NEG_SLOPE 0.2f
#define INV_LN2 1.44269504088896f

typedef unsigned short ushort8_t __attribute__((ext_vector_type(8)));

static __device__ __forceinline__ float lrelu(float v) {
  return v >= 0.f ? v : NEG_SLOPE * v;
}
static __device__ __forceinline__ unsigned short f2bf(float f) {
  unsigned u = __float_as_uint(f);
  u = u + 0x7FFFu + ((u >> 16) & 1u);  // RNE
  return (unsigned short)(u >> 16);
}
static __device__ __forceinline__ float bf2f(unsigned short b) {
  return __uint_as_float(((unsigned)b) << 16);
}
static __device__ __forceinline__ float exp2fast(float x) {
  return __builtin_amdgcn_exp2f(x);
}

// ---- GEMM1: h1b(bf16) = x @ W1, fused as1/ad1 logits (f32, pre-scaled by
// ---- 1/ln2 so downstream softmax uses exp2).  64x256 tile, 8x8/thread. ----
#define BM 64
#define BK 16
__global__ __launch_bounds__(256) void gemm1_kernel(
    const float* __restrict__ A, const float* __restrict__ B,
    unsigned short* __restrict__ Cb, const float* __restrict__ a_src,
    const float* __restrict__ a_dst, float* __restrict__ as1,
    float* __restrict__ ad1, int M) {
  __shared__ float As[BK][68];
  __shared__ float Bs[BK][260];
  const int bm = blockIdx.x * BM;
  const int tid = threadIdx.x;
  const int tx = tid & 31, ty = tid >> 5;
  float acc[8][8] = {};
  for (int k0 = 0; k0 < 128; k0 += BK) {
    {  // stage A tile (64 x 16), transposed
      int r = tid >> 2, c = (tid & 3) << 2;
      int row = bm + r;
      float4 v = (row < M) ? *(const float4*)&A[(size_t)row * 128 + k0 + c]
                           : make_float4(0.f, 0.f, 0.f, 0.f);
      As[c + 0][r] = v.x; As[c + 1][r] = v.y;
      As[c + 2][r] = v.z; As[c + 3][r] = v.w;
    }
    {  // stage B tile (16 x 256)
      int r = tid >> 4, c0 = (tid & 15) << 2;
#pragma unroll
      for (int q = 0; q < 4; q++) {
        int col = c0 + q * 64;
        *(float4*)&Bs[r][col] = *(const float4*)&B[(size_t)(k0 + r) * 256 + col];
      }
    }
    __syncthreads();
#pragma unroll
    for (int kk = 0; kk < BK; ++kk) {
      float a[8], b[8];
      *(float4*)&a[0] = *(const float4*)&As[kk][ty * 8];
      *(float4*)&a[4] = *(const float4*)&As[kk][ty * 8 + 4];
      *(float4*)&b[0] = *(const float4*)&Bs[kk][tx * 4];
      *(float4*)&b[4] = *(const float4*)&Bs[kk][128 + tx * 4];
#pragma unroll
      for (int i = 0; i < 8; i++)
#pragma unroll
        for (int j = 0; j < 8; j++) acc[i][j] += a[i] * b[j];
    }
    __syncthreads();
  }
  // epilogue: bf16 store + fused attention logits (scaled by 1/ln2)
  const int hA = tx >> 3;        // head of col-group A (0..3); group B: 4+hA
  const int co = (tx & 7) << 2;  // within-head col offset
  float wsA[4], wdA[4], wsB[4], wdB[4];
#pragma unroll
  for (int j = 0; j < 4; j++) {
    wsA[j] = a_src[hA * 32 + co + j];
    wdA[j] = a_dst[hA * 32 + co + j];
    wsB[j] = a_src[(4 + hA) * 32 + co + j];
    wdB[j] = a_dst[(4 + hA) * 32 + co + j];
  }
#pragma unroll
  for (int i = 0; i < 8; i++) {
    int row = bm + ty * 8 + i;
    if (row < M) {  // uniform within each 8-lane shfl group
      ushort4 ua, ub;
      ua.x = f2bf(acc[i][0]); ua.y = f2bf(acc[i][1]);
      ua.z = f2bf(acc[i][2]); ua.w = f2bf(acc[i][3]);
      ub.x = f2bf(acc[i][4]); ub.y = f2bf(acc[i][5]);
      ub.z = f2bf(acc[i][6]); ub.w = f2bf(acc[i][7]);
      *(ushort4*)&Cb[(size_t)row * 256 + tx * 4] = ua;
      *(ushort4*)&Cb[(size_t)row * 256 + 128 + tx * 4] = ub;
      float sA = 0.f, dA = 0.f, sB = 0.f, dB = 0.f;
#pragma unroll
      for (int j = 0; j < 4; j++) {
        sA += acc[i][j] * wsA[j];
        dA += acc[i][j] * wdA[j];
        sB += acc[i][4 + j] * wsB[j];
        dB += acc[i][4 + j] * wdB[j];
      }
#pragma unroll
      for (int off = 1; off < 8; off <<= 1) {
        sA += __shfl_xor(sA, off, 64);
        dA += __shfl_xor(dA, off, 64);
        sB += __shfl_xor(sB, off, 64);
        dB += __shfl_xor(dB, off, 64);
      }
      if ((tx & 7) == 0) {
        as1[row * 8 + hA] = sA * INV_LN2;
        as1[row * 8 + 4 + hA] = sB * INV_LN2;
        ad1[row * 8 + hA] = dA * INV_LN2;
        ad1[row * 8 + 4 + hA] = dB * INV_LN2;
      }
    }
  }
}

// ---------------- CSR build ----------------
__global__ void deg_kernel(const int* __restrict__ ei, int E,
                           int* __restrict__ deg) {
  int e = blockIdx.x * blockDim.x + threadIdx.x;
  if (e < E) atomicAdd(&deg[ei[E + e]], 1);
}

// ---- multi-block exclusive scan of (deg+1), SCAN_B nodes per block ----
#define SCAN_B 2048
__global__ __launch_bounds__(256) void scan_p1(const int* __restrict__ deg,
                                               int* __restrict__ blk_sum,
                                               int N) {
  __shared__ int red[256];
  const int t = threadIdx.x;
  const int base = blockIdx.x * SCAN_B;
  int sum = 0;
#pragma unroll
  for (int i = 0; i < SCAN_B / 256; i++) {
    int idx = base + t + i * 256;
    if (idx < N) sum += deg[idx] + 1;
  }
  red[t] = sum;
  __syncthreads();
  for (int off = 128; off > 0; off >>= 1) {
    if (t < off) red[t] += red[t + off];
    __syncthreads();
  }
  if (t == 0) blk_sum[blockIdx.x] = red[0];
}

// single wave: exclusive scan of block sums (nb <= 64), writes total
__global__ __launch_bounds__(64) void scan_p2(int* __restrict__ blk,
                                              int nb,
                                              int* __restrict__ row_start,
                                              int N) {
  int t = threadIdx.x;
  int v = (t < nb) ? blk[t] : 0;
  int inc = v;
#pragma unroll
  for (int off = 1; off < 64; off <<= 1) {
    int u = __shfl_up(inc, off, 64);
    if (t >= off) inc += u;
  }
  if (t < nb) blk[t] = inc - v;  // exclusive offset
  if (t == 63) row_start[N] = inc;  // grand total
}

// per-block local scan + emit row_start, self-loop, cursor
__global__ __launch_bounds__(256) void scan_p3(
    const int* __restrict__ deg, const int* __restrict__ blk_off,
    int* __restrict__ row_start, int* __restrict__ csr,
    int* __restrict__ cursor, int N) {
  __shared__ int tsum[256];
  const int t = threadIdx.x;
  const int base = blockIdx.x * SCAN_B + t * (SCAN_B / 256);
  int v[SCAN_B / 256];
  int s = 0;
#pragma unroll
  for (int i = 0; i < SCAN_B / 256; i++) {
    int idx = base + i;
    v[i] = s;  // local exclusive prefix
    if (idx < N) s += deg[idx] + 1;
  }
  tsum[t] = s;
  __syncthreads();
  for (int off = 1; off < 256; off <<= 1) {
    int x = (t >= off) ? tsum[t - off] : 0;
    __syncthreads();
    tsum[t] += x;
    __syncthreads();
  }
  const int offv = blk_off[blockIdx.x] + ((t == 0) ? 0 : tsum[t - 1]);
#pragma unroll
  for (int i = 0; i < SCAN_B / 256; i++) {
    int idx = base + i;
    if (idx < N) {
      int p = offv + v[i];
      row_start[idx] = p;
      csr[p] = idx;       // self-loop first
      cursor[idx] = p + 1;
    }
  }
}

__global__ void scatter_kernel(const int* __restrict__ ei, int E,
                               int* __restrict__ cursor,
                               int* __restrict__ csr) {
  int e = blockIdx.x * blockDim.x + threadIdx.x;
  if (e < E) {
    int dst = ei[E + e];
    int pos = atomicAdd(&cursor[dst], 1);
    csr[pos] = ei[e];
  }
}

// ---- layer-1 fused: single-pass softmax+aggregate, DEPTH-2 pipelined
// ---- bf16 gather (2 pairs = 4 edges in flight), + bias + ELU +
// ---- W2 projection + alpha2 logits.  One wave per dst. ----
__global__ __launch_bounds__(256) void agg1_kernel(
    const int* __restrict__ row_start, const int* __restrict__ csr,
    const float* __restrict__ as1, const float* __restrict__ ad1,
    const unsigned short* __restrict__ h1b, const float* __restrict__ b1,
    const float* __restrict__ W2, const float* __restrict__ a_src2,
    const float* __restrict__ a_dst2, float* __restrict__ g,
    float* __restrict__ as2, float* __restrict__ ad2, int N) {
  int dst = (int)((blockIdx.x * (size_t)blockDim.x + threadIdx.x) >> 6);
  int lane = threadIdx.x & 63;
  if (dst >= N) return;
  const int beg = row_start[dst];
  const int deg = row_start[dst + 1] - beg;

  // 32 lanes per edge, 2 pair-slots (4 edges) in flight; lane owns 8 channels
  const int l32 = lane & 31, half = lane >> 5;
  const int hA = l32 >> 2;  // head 0..7
  const float adA = ad1[dst * 8 + hA];  // pre-scaled by 1/ln2
  const int dlast = deg - 1;

  float acc[8] = {};
  float s = 0.f;

  // pipeline slots A (edges j, j+1) and B (edges j+2, j+3)
  float eA_, eB_;
  ushort8_t hvA_, hvB_;
  {
    int jj = half > dlast ? dlast : half;
    int src = csr[beg + jj];
    eA_ = as1[src * 8 + hA];
    hvA_ = *(const ushort8_t*)&h1b[(size_t)src * 256 + l32 * 8];
  }
  {
    int jj = 2 + half > dlast ? dlast : 2 + half;
    int src = csr[beg + jj];
    eB_ = as1[src * 8 + hA];
    hvB_ = *(const ushort8_t*)&h1b[(size_t)src * 256 + l32 * 8];
  }

  for (int j = 0; j < deg; j += 4) {
    // consume slot A (edges j+half)
    {
      float w = (j + half < deg) ? exp2fast(lrelu(eA_ + adA)) : 0.f;
      const ushort8_t hv = hvA_;
      if (j + 4 < deg) {  // prefetch A for j+4
        int jj = j + 4 + half;
        if (jj > dlast) jj = dlast;
        int src = csr[beg + jj];
        eA_ = as1[src * 8 + hA];
        hvA_ = *(const ushort8_t*)&h1b[(size_t)src * 256 + l32 * 8];
      }
      s += w;
#pragma unroll
      for (int c = 0; c < 8; c++) acc[c] += w * bf2f(hv[c]);
    }
    // consume slot B (edges j+2+half)
    {
      float w = (j + 2 + half < deg) ? exp2fast(lrelu(eB_ + adA)) : 0.f;
      const ushort8_t hv = hvB_;
      if (j + 6 < deg) {  // prefetch B for j+6
        int jj = j + 6 + half;
        if (jj > dlast) jj = dlast;
        int src = csr[beg + jj];
        eB_ = as1[src * 8 + hA];
        hvB_ = *(const ushort8_t*)&h1b[(size_t)src * 256 + l32 * 8];
      }
      s += w;
#pragma unroll
      for (int c = 0; c < 8; c++) acc[c] += w * bf2f(hv[c]);
    }
  }
  // combine the two halves
  s += __shfl_xor(s, 32, 64);
#pragma unroll
  for (int c = 0; c < 8; c++) acc[c] += __shfl_xor(acc[c], 32, 64);
  const float inv = 1.f / (s + 1e-16f);

  // normalize + bias + ELU (b1: two vector loads)
  float4 b1lo = *(const float4*)&b1[l32 * 8];
  float4 b1hi = *(const float4*)&b1[l32 * 8 + 4];
  float bb[8] = {b1lo.x, b1lo.y, b1lo.z, b1lo.w, b1hi.x, b1hi.y, b1hi.z, b1hi.w};
  float v[8];
#pragma unroll
  for (int c = 0; c < 8; c++) {
    float t = acc[c] * inv + bb[c];
    v[c] = t > 0.f ? t : (__expf(t) - 1.f);
  }
  // fused layer-2 projection: p[10] = elu_h2 @ W2
  float p[10];
#pragma unroll
  for (int c = 0; c < 10; c++) p[c] = 0.f;
#pragma unroll
  for (int cc = 0; cc < 8; cc++) {
    const float* wr = W2 + (size_t)(l32 * 8 + cc) * 10;
    float vc = v[cc];
#pragma unroll
    for (int c = 0; c < 10; c++) p[c] += vc * wr[c];
  }
#pragma unroll
  for (int off = 1; off < 32; off <<= 1) {
#pragma unroll
    for (int c = 0; c < 10; c++) p[c] += __shfl_xor(p[c], off, 64);
  }
  if (lane < 10) g[(size_t)dst * 10 + lane] = p[lane];
  if (lane == 0) {
    float ss = 0.f, dd = 0.f;
#pragma unroll
    for (int c = 0; c < 10; c++) {
      ss += p[c] * a_src2[c];
      dd += p[c] * a_dst2[c];
    }
    as2[dst] = ss * INV_LN2;  // pre-scaled for exp2 in agg2
    ad2[dst] = dd * INV_LN2;
  }
}

// ---- layer-2: single-pass softmax(no-max,exp2) + aggregate, 16 lanes/dst ----
__global__ __launch_bounds__(256) void agg2_kernel(
    const int* __restrict__ row_start, const int* __restrict__ csr,
    const float* __restrict__ as2, const float* __restrict__ ad2,
    const float* __restrict__ g, const float* __restrict__ b2,
    float* __restrict__ out, int N) {
  int dst = (int)((blockIdx.x * (size_t)blockDim.x + threadIdx.x) >> 4);
  int l = threadIdx.x & 15;
  if (dst >= N) return;
  const int beg = row_start[dst];
  const int deg = row_start[dst + 1] - beg;
  const float ad = ad2[dst];
  float s = 0.f;
  float acc[10] = {};
  for (int j = l; j < deg; j += 16) {
    int src = csr[beg + j];
    float w = exp2fast(lrelu(as2[src] + ad));
    s += w;
    const float2* gp = (const float2*)&g[(size_t)src * 10];
#pragma unroll
    for (int q = 0; q < 5; q++) {
      float2 gv = gp[q];
      acc[2 * q + 0] += w * gv.x;
      acc[2 * q + 1] += w * gv.y;
    }
  }
#pragma unroll
  for (int off = 1; off < 16; off <<= 1) {
    s += __shfl_xor(s, off, 16);
#pragma unroll
    for (int c = 0; c < 10; c++) acc[c] += __shfl_xor(acc[c], off, 16);
  }
  const float inv = 1.f / (s + 1e-16f);
  if (l < 10) out[(size_t)dst * 10 + l] = acc[l] * inv + b2[l];
}

extern "C" void kernel_launch(void* const* d_in, const int* in_sizes, int n_in,
                              void* d_out, int out_size, void* d_ws,
                              size_t ws_size, hipStream_t stream) {
  const float* x      = (const float*)d_in[0];
  const int*   ei     = (const int*)d_in[1];
  const float* W1     = (const float*)d_in[2];
  const float* a_src1 = (const float*)d_in[3];
  const float* a_dst1 = (const float*)d_in[4];
  const float* b1     = (const float*)d_in[5];
  const float* W2     = (const float*)d_in[6];
  const float* a_src2 = (const float*)d_in[7];
  const float* a_dst2 = (const float*)d_in[8];
  const float* b2     = (const float*)d_in[9];
  float* out = (float*)d_out;

  const int N = in_sizes[0] / 128;   // 50000
  const int E = in_sizes[1] / 2;     // 800000
  const int nb = (N + SCAN_B - 1) / SCAN_B;  // 25

  unsigned short* h1b = (unsigned short*)d_ws;          // N*256 bf16
  float* as1 = (float*)(h1b + (size_t)N * 256);         // N*8
  float* ad1 = as1 + (size_t)N * 8;                     // N*8
  float* g   = ad1 + (size_t)N * 8;                     // N*10
  float* as2 = g + (size_t)N * 10;                      // N
  float* ad2 = as2 + N;                                 // N
  int* cursor    = (int*)(ad2 + N);                     // N (deg, then cursor)
  int* row_start = cursor + N;                          // N+1
  int* blk_sum   = row_start + N + 1;                   // nb (padded to 64)
  int* csr       = blk_sum + 64;                        // E+N

  hipMemsetAsync(cursor, 0, (size_t)N * 4, stream);

  // ---- CSR build (shared by both layers) ----
  deg_kernel<<<(E + 255) / 256, 256, 0, stream>>>(ei, E, cursor);
  scan_p1<<<nb, 256, 0, stream>>>(cursor, blk_sum, N);
  scan_p2<<<1, 64, 0, stream>>>(blk_sum, nb, row_start, N);
  scan_p3<<<nb, 256, 0, stream>>>(cursor, blk_sum, row_start, csr, cursor, N);
  scatter_kernel<<<(E + 255) / 256, 256, 0, stream>>>(ei, E, cursor, csr);

  // ---- layer-1 projection + fused logits ----
  gemm1_kernel<<<(N + BM - 1) / BM, 256, 0, stream>>>(x, W1, h1b, a_src1,
                                                      a_dst1, as1, ad1, N);

  // ---- fused layer-1 aggregate + ELU + layer-2 projection ----
  agg1_kernel<<<(N + 3) / 4, 256, 0, stream>>>(row_start, csr, as1, ad1, h1b,
                                               b1, W2, a_src2, a_dst2, g, as2,
                                               ad2, N);

  // ---- layer-2 aggregate ----
  agg2_kernel<<<(N * 16 + 255) / 256, 256, 0, stream>>>(row_start, csr, as2,
                                                        ad2, g, b2, out, N);
}